// Round 5
// baseline (138316.919 us; speedup 1.0000x reference)
//
#include <hip/hip_runtime.h>
#include <math.h>

static constexpr int NB  = 1024;
static constexpr int NS  = 100;
static constexpr int NH  = 128;
static constexpr int NTHR = 128;

static constexpr int OUT_MU = 0;
static constexpr int OUT_LV = NB * NS;
static constexpr int OUT_Z  = 2 * NB * NS;
static constexpr int OUT_TI = 3 * NB * NS;
static constexpr int OUT_LP = 4 * NB * NS;

// Literal GRU unit j: gx = x@Wih.T + bih ; gh = h@Whh.T + bhh ; r,z,n ; out
template<int K>
__device__ double gru_unit(const float* __restrict__ Wih, const float* __restrict__ Whh,
                           const float* __restrict__ bih, const float* __restrict__ bhh,
                           const double* __restrict__ x, const double* __restrict__ h, int j)
{
    const float* wr = Wih + (size_t)j        * K;
    const float* wz = Wih + (size_t)(NH + j) * K;
    const float* wn = Wih + (size_t)(2*NH+j) * K;
    double xr = 0.0, xz = 0.0, xn = 0.0;
    for (int k = 0; k < K; ++k) {
        double xv = x[k];
        xr += (double)wr[k] * xv;
        xz += (double)wz[k] * xv;
        xn += (double)wn[k] * xv;
    }
    const float* ur = Whh + (size_t)j        * NH;
    const float* uz = Whh + (size_t)(NH + j) * NH;
    const float* un = Whh + (size_t)(2*NH+j) * NH;
    double hr = 0.0, hz = 0.0, hn = 0.0;
    for (int k = 0; k < NH; ++k) {
        double hv = h[k];
        hr += (double)ur[k] * hv;
        hz += (double)uz[k] * hv;
        hn += (double)un[k] * hv;
    }
    double r = 1.0 / (1.0 + exp(-((xr + (double)bih[j])      + (hr + (double)bhh[j]))));
    double z = 1.0 / (1.0 + exp(-((xz + (double)bih[NH+j])   + (hz + (double)bhh[NH+j]))));
    double n = tanh((xn + (double)bih[2*NH+j]) + r * (hn + (double)bhh[2*NH+j]));
    return (1.0 - z) * n + z * h[j];
}

// Literal head logit for one s: sum_h act( sum_k inst_h[s,k]*W[k,h] + q[h] ) * v[h]
// W first-half accessed with thread-uniform addresses (h uniform loop, k unrolled).
template<bool TANH>
__device__ float head_logit(const float* __restrict__ W, const float* __restrict__ rih,
                            const double* __restrict__ q, const float* __restrict__ v)
{
    double acc = 0.0;
    for (int h = 0; h < NH; h += 4) {
        float a0 = 0.f, a1 = 0.f, a2 = 0.f, a3 = 0.f;
        #pragma unroll
        for (int k = 0; k < NH; ++k) {
            const float4 w = *reinterpret_cast<const float4*>(W + (size_t)k * NH + h);
            float iv = rih[k];
            a0 = fmaf(iv, w.x, a0); a1 = fmaf(iv, w.y, a1);
            a2 = fmaf(iv, w.z, a2); a3 = fmaf(iv, w.w, a3);
        }
        double p0 = (double)a0 + q[h+0];
        double p1 = (double)a1 + q[h+1];
        double p2 = (double)a2 + q[h+2];
        double p3 = (double)a3 + q[h+3];
        if (TANH) {
            acc += tanh(p0)*(double)v[h] + tanh(p1)*(double)v[h+1]
                 + tanh(p2)*(double)v[h+2] + tanh(p3)*(double)v[h+3];
        } else {
            acc += fmax(p0,0.0)*(double)v[h] + fmax(p1,0.0)*(double)v[h+1]
                 + fmax(p2,0.0)*(double)v[h+2] + fmax(p3,0.0)*(double)v[h+3];
        }
    }
    return (float)acc;
}

__global__ __launch_bounds__(NTHR) void vae_probe(
    const float* __restrict__ instance, const int* __restrict__ sol1,
    const int* __restrict__ sol2, const float* __restrict__ eps,
    const float* __restrict__ emb_i_W, const float* __restrict__ emb_i_b,
    const float* __restrict__ emb_r_W, const float* __restrict__ emb_r_b,
    const float* __restrict__ attn_W, const float* __restrict__ attn_v,
    const float* __restrict__ gru_Wih, const float* __restrict__ gru_Whh,
    const float* __restrict__ gru_bih, const float* __restrict__ gru_bhh,
    const float* __restrict__ grud_Wih, const float* __restrict__ grud_Whh,
    const float* __restrict__ grud_bih, const float* __restrict__ grud_bhh,
    const float* __restrict__ efc1_W, const float* __restrict__ efc1_b,
    const float* __restrict__ efc2_W, const float* __restrict__ efc2_b,
    const float* __restrict__ ptr_W, const float* __restrict__ ptr_v,
    const float* __restrict__ pfc1_W, const float* __restrict__ pfc1_b,
    const float* __restrict__ pfc2_W, const float* __restrict__ pfc2_b,
    float* __restrict__ out)
{
    __shared__ double s_x[360];        // enc: [ref|ctx]; dec: [ctx|Z|ref]
    __shared__ double s_h1[NH], s_h2[NH], s_q[NH], s_fch[256], s_fco[NH];
    __shared__ float  s_ih[NS * 129];  // literal inst_h, padded rows
    __shared__ float  s_c0[NS], s_c1[NS], s_msk[NS], s_lg[NS], s_a[NS];
    __shared__ float  s_va[NH], s_vp[NH];
    __shared__ double s_rc[2];         // decoder carry coords
    __shared__ double s_ms[2];         // mx, se scratch

    const int tid = threadIdx.x;
    const int b = blockIdx.x;

    // ---------- init ----------
    if (tid < NS) {
        s_c0[tid] = instance[(size_t)(b * NS + tid) * 2 + 0];
        s_c1[tid] = instance[(size_t)(b * NS + tid) * 2 + 1];
    }
    if (tid < NH) {
        s_va[tid] = attn_v[tid];
        s_vp[tid] = ptr_v[tid];
        s_h1[tid] = 0.0;
        s_h2[tid] = 0.0;
    }
    float* tmp = (float*)s_fch;  // stage emb_i here (fch unused until decoder)
    if (tid < NH) {
        tmp[tid]        = emb_i_W[2*tid];
        tmp[NH + tid]   = emb_i_W[2*tid + 1];
        tmp[2*NH + tid] = emb_i_b[tid];
    }
    __syncthreads();
    // literal inst_h[s][k] = c0*emb_i_W[k,0] + c1*emb_i_W[k,1] + emb_i_b[k], f32
    if (tid < NH) {
        for (int s = 0; s < NS; ++s)
            s_ih[s * 129 + tid] = fmaf(s_c0[s], tmp[tid], fmaf(s_c1[s], tmp[NH + tid], tmp[2*NH + tid]));
    }
    __syncthreads();
    float rih[NH];
    if (tid < NS) {
        #pragma unroll
        for (int k = 0; k < NH; ++k) rih[k] = s_ih[tid * 129 + k];
    }
    // initial encoder ref_h = emb_r(coords of sol1[:,0])
    {
        int sp = sol1[b * NS + 0];
        double rc0 = (double)s_c0[sp], rc1 = (double)s_c1[sp];
        if (tid < NH)
            s_x[tid] = rc0 * (double)emb_r_W[2*tid] + rc1 * (double)emb_r_W[2*tid+1] + (double)emb_r_b[tid];
    }
    __syncthreads();

    // ---------- encoder ----------
    for (int t = 1; t < NS; ++t) {
        double h1n = 0.0;
        if (tid < NH) h1n = gru_unit<128>(gru_Wih, gru_Whh, gru_bih, gru_bhh, s_x, s_h1, tid);
        __syncthreads();
        if (tid < NH) s_h1[tid] = h1n;
        __syncthreads();
        // q[h] = sum_k h1[k] * attn_W[128+k][h]  (pure rnn half)
        if (tid < NH) {
            const float* col = attn_W + (size_t)NH * NH + tid;
            double a = 0.0;
            for (int k = 0; k < NH; ++k) a += (double)col[(size_t)k * NH] * s_h1[k];
            s_q[tid] = a;
        }
        __syncthreads();
        if (tid < NS) s_lg[tid] = head_logit<false>(attn_W, rih, s_q, s_va);
        __syncthreads();
        // attention softmax (literal, no mask)
        if (tid == 0) {
            double mx = -1e308;
            for (int s = 0; s < NS; ++s) if ((double)s_lg[s] > mx) mx = (double)s_lg[s];
            s_ms[0] = mx;
        }
        __syncthreads();
        if (tid < NS) s_a[tid] = (float)exp((double)s_lg[tid] - s_ms[0]);
        __syncthreads();
        if (tid == 0) {
            double se = 0.0;
            for (int s = 0; s < NS; ++s) se += (double)s_a[s];
            s_ms[1] = se;
        }
        __syncthreads();
        if (tid < NS) s_a[tid] = (float)((double)s_a[tid] / s_ms[1]);
        __syncthreads();
        // literal context + new ref_h
        {
            int sp = sol1[b * NS + t];
            if (tid < NH) {
                double a = 0.0;
                for (int s = 0; s < NS; ++s) a += (double)s_a[s] * (double)s_ih[s * 129 + tid];
                double rc0 = (double)s_c0[sp], rc1 = (double)s_c1[sp];
                double nr = rc0 * (double)emb_r_W[2*tid] + rc1 * (double)emb_r_W[2*tid+1] + (double)emb_r_b[tid];
                s_x[NH + tid] = a;   // context second
                s_x[tid] = nr;       // new ref first
            }
        }
        __syncthreads();
        double h2n = 0.0;
        if (tid < NH) h2n = gru_unit<256>(grud_Wih, grud_Whh, grud_bih, grud_bhh, s_x, s_h2, tid);
        __syncthreads();
        if (tid < NH) s_h2[tid] = h2n;
        __syncthreads();
    }

    // ---------- epilogue: mu, lv, Z ----------
    if (tid < NS) {
        int s = tid;
        double mu = 0.0, lv = 0.0;
        const float* w1r = efc1_W + (size_t)s * NH;
        const float* w2r = efc2_W + (size_t)s * NH;
        for (int k = 0; k < NH; ++k) {
            mu += (double)w1r[k] * s_h2[k];
            lv += (double)w2r[k] * s_h2[k];
        }
        mu += (double)efc1_b[s];
        lv += (double)efc2_b[s];
        double z = mu + (double)eps[(size_t)b * NS + s] * exp(0.5 * lv);
        out[OUT_MU + b * NS + s] = (float)mu;
        out[OUT_LV + b * NS + s] = (float)lv;
        out[OUT_Z  + b * NS + s] = (float)z;
        s_x[NH + s] = z;   // decoder Z slot [128..227]
    }
    __syncthreads();

    // ---------- decoder init ----------
    if (tid < NS) s_msk[tid] = 1.f;
    if (tid < NH) s_h1[tid] = 0.0;
    __syncthreads();
    if (tid == 0) {
        int s0 = sol2[b * NS + 0];
        s_msk[s0] = 0.f;
        s_rc[0] = (double)s_c0[s0];
        s_rc[1] = (double)s_c1[s0];
        out[OUT_TI + b * NS + 0] = (float)s0;
    }
    __syncthreads();

    // ---------- decoder ----------
    for (int t = 1; t < NS; ++t) {
        if (tid < NH)
            s_x[228 + tid] = s_rc[0] * (double)emb_r_W[2*tid] + s_rc[1] * (double)emb_r_W[2*tid+1]
                           + (double)emb_r_b[tid];
        __syncthreads();
        double h1n = 0.0;
        if (tid < NH) h1n = gru_unit<128>(gru_Wih, gru_Whh, gru_bih, gru_bhh, s_x + 228, s_h1, tid);
        __syncthreads();
        if (tid < NH) s_h1[tid] = h1n;
        __syncthreads();
        if (tid < NH) {
            const float* col = attn_W + (size_t)NH * NH + tid;
            double a = 0.0;
            for (int k = 0; k < NH; ++k) a += (double)col[(size_t)k * NH] * s_h1[k];
            s_q[tid] = a;
        }
        __syncthreads();
        if (tid < NS) s_lg[tid] = head_logit<false>(attn_W, rih, s_q, s_va);
        __syncthreads();
        if (tid == 0) {
            double mx = -1e308;
            for (int s = 0; s < NS; ++s) if ((double)s_lg[s] > mx) mx = (double)s_lg[s];
            s_ms[0] = mx;
        }
        __syncthreads();
        if (tid < NS) s_a[tid] = (float)exp((double)s_lg[tid] - s_ms[0]);
        __syncthreads();
        if (tid == 0) {
            double se = 0.0;
            for (int s = 0; s < NS; ++s) se += (double)s_a[s];
            s_ms[1] = se;
        }
        __syncthreads();
        if (tid < NS) s_a[tid] = (float)((double)s_a[tid] / s_ms[1]);
        __syncthreads();
        if (tid < NH) {
            double a = 0.0;
            for (int s = 0; s < NS; ++s) a += (double)s_a[s] * (double)s_ih[s * 129 + tid];
            s_x[tid] = a;   // decoder ctx at [0..127]
        }
        __syncthreads();
        // pfc1: 256 rows, K=356 over [ctx|Z|ref]
        for (int i = tid; i < 256; i += NTHR) {
            const float* wr = pfc1_W + (size_t)i * 356;
            double a = 0.0;
            for (int k = 0; k < 356; ++k) a += (double)wr[k] * s_x[k];
            s_fch[i] = a + (double)pfc1_b[i];
        }
        __syncthreads();
        // pfc2: 128 rows, K=256
        if (tid < NH) {
            const float* wr = pfc2_W + (size_t)tid * 256;
            double a = 0.0;
            for (int k = 0; k < 256; ++k) a += (double)wr[k] * s_fch[k];
            s_fco[tid] = a + (double)pfc2_b[tid];
        }
        __syncthreads();
        // q2[h] = sum_k fc_out[k] * ptr_W[128+k][h]
        if (tid < NH) {
            const float* col = ptr_W + (size_t)NH * NH + tid;
            double a = 0.0;
            for (int k = 0; k < NH; ++k) a += (double)col[(size_t)k * NH] * s_fco[k];
            s_q[tid] = a;
        }
        __syncthreads();
        if (tid < NS) s_lg[tid] = head_logit<true>(ptr_W, rih, s_q, s_vp);
        __syncthreads();
        // literal masked softmax / argmax / logp (serial compares, parallel exps)
        if (tid == 0) {
            double mx = -1e308;
            for (int s = 0; s < NS; ++s) {
                double v = (s_msk[s] > 0.f) ? (double)s_lg[s] : -1e308;  // == lg + log(mask)
                if (v > mx) mx = v;
            }
            s_ms[0] = mx;
        }
        __syncthreads();
        if (tid < NS)
            s_a[tid] = (s_msk[tid] > 0.f) ? (float)exp((double)s_lg[tid] - s_ms[0]) : 0.f;
        __syncthreads();
        if (tid == 0) {
            int pt = sol2[b * NS + t];
            double se = 0.0;
            for (int s = 0; s < NS; ++s) se += (double)s_a[s];
            double bp = -1.0; int bidx = 0;
            for (int s = 0; s < NS; ++s) {
                double p = (double)s_a[s] / se;   // probs; argmax first-max like jnp.argmax
                if (p > bp) { bp = p; bidx = s; }
            }
            double logp = log(((double)s_a[pt]) / se);
            out[OUT_TI + b * NS + t]              = (float)bidx;
            out[OUT_LP + b * (NS - 1) + (t - 1)]  = (float)logp;
            s_msk[pt] = 0.f;
            s_rc[0] = (double)s_c0[pt];
            s_rc[1] = (double)s_c1[pt];
        }
        __syncthreads();
    }
}

extern "C" void kernel_launch(void* const* d_in, const int* in_sizes, int n_in,
                              void* d_out, int out_size, void* d_ws, size_t ws_size,
                              hipStream_t stream)
{
    (void)in_sizes; (void)n_in; (void)out_size; (void)d_ws; (void)ws_size;
    vae_probe<<<NB, NTHR, 0, stream>>>(
        (const float*)d_in[0], (const int*)d_in[1], (const int*)d_in[2], (const float*)d_in[3],
        (const float*)d_in[4], (const float*)d_in[5], (const float*)d_in[6], (const float*)d_in[7],
        (const float*)d_in[8], (const float*)d_in[9], (const float*)d_in[10], (const float*)d_in[11],
        (const float*)d_in[12], (const float*)d_in[13], (const float*)d_in[14], (const float*)d_in[15],
        (const float*)d_in[16], (const float*)d_in[17], (const float*)d_in[18], (const float*)d_in[19],
        (const float*)d_in[20], (const float*)d_in[21], (const float*)d_in[22], (const float*)d_in[23],
        (const float*)d_in[24], (const float*)d_in[25], (const float*)d_in[26], (const float*)d_in[27],
        (float*)d_out);
}

// Round 7
// 126836.145 us; speedup vs baseline: 1.0905x; 1.0905x over previous
//
#include <hip/hip_runtime.h>
#include <math.h>

static constexpr int NB  = 1024;
static constexpr int NS  = 100;
static constexpr int NH  = 128;
static constexpr int NTHR = 256;

static constexpr int OUT_MU = 0;
static constexpr int OUT_LV = NB * NS;
static constexpr int OUT_Z  = 2 * NB * NS;
static constexpr int OUT_TI = 3 * NB * NS;
static constexpr int OUT_LP = 4 * NB * NS;

// f64 dot of an f32 global row (C4 float4 chunks) vs f64 LDS vector, k ascending.
template<int C4>
__device__ __forceinline__ double dotw(const float* __restrict__ w, const double* __restrict__ x)
{
    const float4* W = reinterpret_cast<const float4*>(w);
    double a = 0.0;
    #pragma unroll 8
    for (int c = 0; c < C4; ++c) {
        float4 u = W[c];
        const double* p = x + 4 * c;
        a = fma((double)u.x, p[0], a);
        a = fma((double)u.y, p[1], a);
        a = fma((double)u.z, p[2], a);
        a = fma((double)u.w, p[3], a);
    }
    return a;
}

// GRU nonlinearity combine: pa = x-side gate dots, pb = h-side gate dots.
__device__ __forceinline__ void gru_combine(const float* __restrict__ bih, const float* __restrict__ bhh,
        const double* __restrict__ pa, const double* __restrict__ pb, double* __restrict__ h, int j)
{
    double r = 1.0 / (1.0 + exp(-((pa[j]        + (double)bih[j])        + (pb[j]        + (double)bhh[j]))));
    double z = 1.0 / (1.0 + exp(-((pa[NH + j]   + (double)bih[NH + j])   + (pb[NH + j]   + (double)bhh[NH + j]))));
    double n = tanh((pa[2*NH + j] + (double)bih[2*NH + j]) + r * (pb[2*NH + j] + (double)bhh[2*NH + j]));
    h[j] = (1.0 - z) * n + z * h[j];
}

// Head partial: thread (s = tid&127, half = tid>>7) computes the h-half sum for
// position s. f32 inner chain bit-identical to round-5 (k ascending, one fmaf
// per (h,k), inline ih expression).
template<bool TANH>
__device__ __forceinline__ void head_phase(const float* __restrict__ W, const float* __restrict__ vf,
        const double* __restrict__ qp,
        const float* __restrict__ c0, const float* __restrict__ c1,
        const float* __restrict__ wi0, const float* __restrict__ wi1, const float* __restrict__ bi,
        double* __restrict__ part, int tid)
{
    int s = tid & (NH - 1), half = tid >> 7;
    if (s >= NS) return;
    float acc[64];
    #pragma unroll
    for (int i = 0; i < 64; ++i) acc[i] = 0.f;
    float c0s = c0[s], c1s = c1[s];
    const float* Wh = W + half * 64;
    for (int k = 0; k < NH; ++k) {
        float iv = fmaf(c0s, wi0[k], fmaf(c1s, wi1[k], bi[k]));
        const float4* Wk = reinterpret_cast<const float4*>(Wh + (size_t)k * NH);
        #pragma unroll
        for (int c = 0; c < 16; ++c) {
            float4 u = Wk[c];
            acc[4*c+0] = fmaf(iv, u.x, acc[4*c+0]);
            acc[4*c+1] = fmaf(iv, u.y, acc[4*c+1]);
            acc[4*c+2] = fmaf(iv, u.z, acc[4*c+2]);
            acc[4*c+3] = fmaf(iv, u.w, acc[4*c+3]);
        }
    }
    const int h0 = half * 64;
    double a = 0.0;
    #pragma unroll 4
    for (int i = 0; i < 64; ++i) {
        double pre = (double)acc[i] + (qp[h0 + i] + qp[NH + h0 + i]);
        double act = TANH ? tanh(pre) : fmax(pre, 0.0);
        a = fma(act, (double)vf[h0 + i], a);
    }
    part[half * NH + s] = a;
}

__global__ __launch_bounds__(NTHR) void vae_v7(
    const float* __restrict__ instance, const int* __restrict__ sol1,
    const int* __restrict__ sol2, const float* __restrict__ eps,
    const float* __restrict__ emb_i_W, const float* __restrict__ emb_i_b,
    const float* __restrict__ emb_r_W, const float* __restrict__ emb_r_b,
    const float* __restrict__ attn_W, const float* __restrict__ attn_v,
    const float* __restrict__ gru_Wih, const float* __restrict__ gru_Whh,
    const float* __restrict__ gru_bih, const float* __restrict__ gru_bhh,
    const float* __restrict__ grud_Wih, const float* __restrict__ grud_Whh,
    const float* __restrict__ grud_bih, const float* __restrict__ grud_bhh,
    const float* __restrict__ efc1_W, const float* __restrict__ efc1_b,
    const float* __restrict__ efc2_W, const float* __restrict__ efc2_b,
    const float* __restrict__ ptr_W, const float* __restrict__ ptr_v,
    const float* __restrict__ pfc1_W, const float* __restrict__ pfc1_b,
    const float* __restrict__ pfc2_W, const float* __restrict__ pfc2_b,
    float* __restrict__ out)
{
    __shared__ double s_x[360];                 // enc: [ref|ctx]; dec: [ctx|Z|ref]
    __shared__ double s_h1[NH], s_h2[NH], s_fco[NH];
    __shared__ double s_fch[256];
    __shared__ double s_pa[3 * NH], s_pb[3 * NH];
    __shared__ float  s_lg[NS], s_a[NS];        // f32 logits / exps-probs (round-5 semantics)
    __shared__ float  s_c0[NS], s_c1[NS], s_msk[NS];
    __shared__ float  t_wi0[NH], t_wi1[NH], t_bi[NH];
    __shared__ float  t_wr0[NH], t_wr1[NH], t_br[NH];
    __shared__ float  t_va[NH], t_vp[NH];
    __shared__ double s_rc[2];
    __shared__ double s_ms[2];                  // mx, se scratch (serial phases)

    const int tid = threadIdx.x;
    const int b = blockIdx.x;
    const int j = tid & (NH - 1);
    const int half = tid >> 7;

    // ---------- init ----------
    if (tid < NH) {
        t_wi0[tid] = emb_i_W[2*tid]; t_wi1[tid] = emb_i_W[2*tid+1]; t_bi[tid] = emb_i_b[tid];
        t_wr0[tid] = emb_r_W[2*tid]; t_wr1[tid] = emb_r_W[2*tid+1]; t_br[tid] = emb_r_b[tid];
        t_va[tid] = attn_v[tid]; t_vp[tid] = ptr_v[tid];
        s_h1[tid] = 0.0; s_h2[tid] = 0.0;
    }
    if (tid < NS) {
        s_c0[tid] = instance[(size_t)(b * NS + tid) * 2 + 0];
        s_c1[tid] = instance[(size_t)(b * NS + tid) * 2 + 1];
    }
    __syncthreads();
    if (tid < NH) {   // initial encoder ref_h
        int sp = sol1[b * NS + 0];
        s_x[tid] = (double)s_c0[sp] * (double)t_wr0[tid] + (double)s_c1[sp] * (double)t_wr1[tid] + (double)t_br[tid];
    }
    __syncthreads();

    // ---------- encoder ----------
    for (int t = 1; t < NS; ++t) {
        // GRU1 gate dots
        if (half == 0) {
            s_pa[j]        = dotw<32>(gru_Wih + (size_t)j          * NH, s_x);
            s_pa[NH + j]   = dotw<32>(gru_Wih + (size_t)(NH + j)   * NH, s_x);
            s_pa[2*NH + j] = dotw<32>(gru_Wih + (size_t)(2*NH + j) * NH, s_x);
        } else {
            s_pb[j]        = dotw<32>(gru_Whh + (size_t)j          * NH, s_h1);
            s_pb[NH + j]   = dotw<32>(gru_Whh + (size_t)(NH + j)   * NH, s_h1);
            s_pb[2*NH + j] = dotw<32>(gru_Whh + (size_t)(2*NH + j) * NH, s_h1);
        }
        __syncthreads();
        if (tid < NH) gru_combine(gru_bih, gru_bhh, s_pa, s_pb, s_h1, tid);
        __syncthreads();
        {   // q partials over k-halves (coalesced column reads)
            const float* col = attn_W + (size_t)NH * NH + j;
            double a = 0.0; const int k0 = half * 64;
            for (int k = k0; k < k0 + 64; ++k) a = fma((double)col[(size_t)k * NH], s_h1[k], a);
            s_pa[half * NH + j] = a;
        }
        __syncthreads();
        head_phase<false>(attn_W, t_va, s_pa, s_c0, s_c1, t_wi0, t_wi1, t_bi, s_pb, tid);
        __syncthreads();
        if (tid < NS) s_lg[tid] = (float)(s_pb[tid] + s_pb[NH + tid]);   // f32 logits (round-5)
        __syncthreads();
        // ---- attention softmax, round-5 serial semantics ----
        if (tid == 0) {
            double mx = -1e308;
            for (int s = 0; s < NS; ++s) if ((double)s_lg[s] > mx) mx = (double)s_lg[s];
            s_ms[0] = mx;
        }
        __syncthreads();
        if (tid < NS) s_a[tid] = (float)exp((double)s_lg[tid] - s_ms[0]);
        __syncthreads();
        if (tid == 0) {
            double se = 0.0;
            for (int s = 0; s < NS; ++s) se += (double)s_a[s];
            s_ms[1] = se;
        }
        __syncthreads();
        if (tid < NS) s_a[tid] = (float)((double)s_a[tid] / s_ms[1]);
        __syncthreads();
        if (tid < NH) {   // context + new ref_h
            double a = 0.0;
            for (int s = 0; s < NS; ++s) {
                float ih = fmaf(s_c0[s], t_wi0[tid], fmaf(s_c1[s], t_wi1[tid], t_bi[tid]));
                a += (double)s_a[s] * (double)ih;
            }
            int sp = sol1[b * NS + t];
            s_x[NH + tid] = a;
            s_x[tid] = (double)s_c0[sp] * (double)t_wr0[tid] + (double)s_c1[sp] * (double)t_wr1[tid] + (double)t_br[tid];
        }
        __syncthreads();
        // GRUd (K=256)
        if (half == 0) {
            s_pa[j]        = dotw<64>(grud_Wih + (size_t)j          * 256, s_x);
            s_pa[NH + j]   = dotw<64>(grud_Wih + (size_t)(NH + j)   * 256, s_x);
            s_pa[2*NH + j] = dotw<64>(grud_Wih + (size_t)(2*NH + j) * 256, s_x);
        } else {
            s_pb[j]        = dotw<32>(grud_Whh + (size_t)j          * NH, s_h2);
            s_pb[NH + j]   = dotw<32>(grud_Whh + (size_t)(NH + j)   * NH, s_h2);
            s_pb[2*NH + j] = dotw<32>(grud_Whh + (size_t)(2*NH + j) * NH, s_h2);
        }
        __syncthreads();
        if (tid < NH) gru_combine(grud_bih, grud_bhh, s_pa, s_pb, s_h2, tid);
        __syncthreads();
    }

    // ---------- epilogue: mu, lv, Z ----------
    if (tid < NS) {
        int s = tid;
        double mu = dotw<32>(efc1_W + (size_t)s * NH, s_h2) + (double)efc1_b[s];
        double lv = dotw<32>(efc2_W + (size_t)s * NH, s_h2) + (double)efc2_b[s];
        double z  = mu + (double)eps[(size_t)b * NS + s] * exp(0.5 * lv);
        out[OUT_MU + b * NS + s] = (float)mu;
        out[OUT_LV + b * NS + s] = (float)lv;
        out[OUT_Z  + b * NS + s] = (float)z;
        s_x[NH + s] = z;   // decoder Z slot [128..227]
    }
    if (tid < NS) s_msk[tid] = 1.f;
    if (tid < NH) s_h1[tid] = 0.0;
    __syncthreads();
    if (tid == 0) {
        int s0 = sol2[b * NS + 0];
        s_msk[s0] = 0.f;
        s_rc[0] = (double)s_c0[s0];
        s_rc[1] = (double)s_c1[s0];
        out[OUT_TI + b * NS + 0] = (float)s0;
    }
    __syncthreads();

    // ---------- decoder ----------
    for (int t = 1; t < NS; ++t) {
        if (tid < NH)
            s_x[228 + tid] = s_rc[0] * (double)t_wr0[tid] + s_rc[1] * (double)t_wr1[tid] + (double)t_br[tid];
        __syncthreads();
        // GRU1 on ref (K=128)
        if (half == 0) {
            s_pa[j]        = dotw<32>(gru_Wih + (size_t)j          * NH, s_x + 228);
            s_pa[NH + j]   = dotw<32>(gru_Wih + (size_t)(NH + j)   * NH, s_x + 228);
            s_pa[2*NH + j] = dotw<32>(gru_Wih + (size_t)(2*NH + j) * NH, s_x + 228);
        } else {
            s_pb[j]        = dotw<32>(gru_Whh + (size_t)j          * NH, s_h1);
            s_pb[NH + j]   = dotw<32>(gru_Whh + (size_t)(NH + j)   * NH, s_h1);
            s_pb[2*NH + j] = dotw<32>(gru_Whh + (size_t)(2*NH + j) * NH, s_h1);
        }
        __syncthreads();
        if (tid < NH) gru_combine(gru_bih, gru_bhh, s_pa, s_pb, s_h1, tid);
        __syncthreads();
        {   // q partials (attn)
            const float* col = attn_W + (size_t)NH * NH + j;
            double a = 0.0; const int k0 = half * 64;
            for (int k = k0; k < k0 + 64; ++k) a = fma((double)col[(size_t)k * NH], s_h1[k], a);
            s_pa[half * NH + j] = a;
        }
        __syncthreads();
        head_phase<false>(attn_W, t_va, s_pa, s_c0, s_c1, t_wi0, t_wi1, t_bi, s_pb, tid);
        __syncthreads();
        if (tid < NS) s_lg[tid] = (float)(s_pb[tid] + s_pb[NH + tid]);
        __syncthreads();
        if (tid == 0) {
            double mx = -1e308;
            for (int s = 0; s < NS; ++s) if ((double)s_lg[s] > mx) mx = (double)s_lg[s];
            s_ms[0] = mx;
        }
        __syncthreads();
        if (tid < NS) s_a[tid] = (float)exp((double)s_lg[tid] - s_ms[0]);
        __syncthreads();
        if (tid == 0) {
            double se = 0.0;
            for (int s = 0; s < NS; ++s) se += (double)s_a[s];
            s_ms[1] = se;
        }
        __syncthreads();
        if (tid < NS) s_a[tid] = (float)((double)s_a[tid] / s_ms[1]);
        __syncthreads();
        if (tid < NH) {   // context -> s_x[0..127]
            double a = 0.0;
            for (int s = 0; s < NS; ++s) {
                float ih = fmaf(s_c0[s], t_wi0[tid], fmaf(s_c1[s], t_wi1[tid], t_bi[tid]));
                a += (double)s_a[s] * (double)ih;
            }
            s_x[tid] = a;
        }
        __syncthreads();
        {   // pfc1: 256 rows, K=356 over [ctx|Z|ref]
            double a = dotw<89>(pfc1_W + (size_t)tid * 356, s_x);
            s_fch[tid] = a + (double)pfc1_b[tid];
        }
        __syncthreads();
        {   // pfc2 partials: K=256 split in halves
            double a = dotw<32>(pfc2_W + (size_t)j * 256 + half * 128, s_fch + half * 128);
            s_pa[half * NH + j] = a;
        }
        __syncthreads();
        if (tid < NH) s_fco[tid] = (s_pa[tid] + s_pa[NH + tid]) + (double)pfc2_b[tid];
        __syncthreads();
        {   // q2 partials (ptr)
            const float* col = ptr_W + (size_t)NH * NH + j;
            double a = 0.0; const int k0 = half * 64;
            for (int k = k0; k < k0 + 64; ++k) a = fma((double)col[(size_t)k * NH], s_fco[k], a);
            s_pa[half * NH + j] = a;
        }
        __syncthreads();
        head_phase<true>(ptr_W, t_vp, s_pa, s_c0, s_c1, t_wi0, t_wi1, t_bi, s_pb, tid);
        __syncthreads();
        if (tid < NS) s_lg[tid] = (float)(s_pb[tid] + s_pb[NH + tid]);
        __syncthreads();
        // ---- masked softmax / argmax / logp, round-5 serial semantics ----
        if (tid == 0) {
            double mx = -1e308;
            for (int s = 0; s < NS; ++s) {
                double v = (s_msk[s] > 0.f) ? (double)s_lg[s] : -1e308;
                if (v > mx) mx = v;
            }
            s_ms[0] = mx;
        }
        __syncthreads();
        if (tid < NS)
            s_a[tid] = (s_msk[tid] > 0.f) ? (float)exp((double)s_lg[tid] - s_ms[0]) : 0.f;
        __syncthreads();
        if (tid == 0) {
            int pt = sol2[b * NS + t];
            double se = 0.0;
            for (int s = 0; s < NS; ++s) se += (double)s_a[s];
            double bp = -1.0; int bidx = 0;
            for (int s = 0; s < NS; ++s) {
                double p = (double)s_a[s] / se;
                if (p > bp) { bp = p; bidx = s; }
            }
            double logp = log(((double)s_a[pt]) / se);
            out[OUT_TI + b * NS + t]             = (float)bidx;
            out[OUT_LP + b * (NS - 1) + (t - 1)] = (float)logp;
            s_msk[pt] = 0.f;
            s_rc[0] = (double)s_c0[pt];
            s_rc[1] = (double)s_c1[pt];
        }
        __syncthreads();
    }
}

extern "C" void kernel_launch(void* const* d_in, const int* in_sizes, int n_in,
                              void* d_out, int out_size, void* d_ws, size_t ws_size,
                              hipStream_t stream)
{
    (void)in_sizes; (void)n_in; (void)out_size; (void)d_ws; (void)ws_size;
    vae_v7<<<NB, NTHR, 0, stream>>>(
        (const float*)d_in[0], (const int*)d_in[1], (const int*)d_in[2], (const float*)d_in[3],
        (const float*)d_in[4], (const float*)d_in[5], (const float*)d_in[6], (const float*)d_in[7],
        (const float*)d_in[8], (const float*)d_in[9], (const float*)d_in[10], (const float*)d_in[11],
        (const float*)d_in[12], (const float*)d_in[13], (const float*)d_in[14], (const float*)d_in[15],
        (const float*)d_in[16], (const float*)d_in[17], (const float*)d_in[18], (const float*)d_in[19],
        (const float*)d_in[20], (const float*)d_in[21], (const float*)d_in[22], (const float*)d_in[23],
        (const float*)d_in[24], (const float*)d_in[25], (const float*)d_in[26], (const float*)d_in[27],
        (float*)d_out);
}

// Round 8
// 45414.502 us; speedup vs baseline: 3.0457x; 2.7929x over previous
//
#include <hip/hip_runtime.h>
#include <math.h>

static constexpr int NB  = 1024;
static constexpr int NS  = 100;
static constexpr int NH  = 128;
static constexpr int NTHR = 256;

static constexpr int OUT_MU = 0;
static constexpr int OUT_LV = NB * NS;
static constexpr int OUT_Z  = 2 * NB * NS;
static constexpr int OUT_TI = 3 * NB * NS;
static constexpr int OUT_LP = 4 * NB * NS;

// f64 dot of an f32 global row (C4 float4 chunks) vs f64 LDS vector, k ascending.
template<int C4>
__device__ __forceinline__ double dotw(const float* __restrict__ w, const double* __restrict__ x)
{
    const float4* W = reinterpret_cast<const float4*>(w);
    double a = 0.0;
    #pragma unroll 8
    for (int c = 0; c < C4; ++c) {
        float4 u = W[c];
        const double* p = x + 4 * c;
        a = fma((double)u.x, p[0], a);
        a = fma((double)u.y, p[1], a);
        a = fma((double)u.z, p[2], a);
        a = fma((double)u.w, p[3], a);
    }
    return a;
}

// GRU nonlinearity combine: pa = x-side gate dots, pb = h-side gate dots.
__device__ __forceinline__ void gru_combine(const float* __restrict__ bih, const float* __restrict__ bhh,
        const double* __restrict__ pa, const double* __restrict__ pb, double* __restrict__ h, int j)
{
    double r = 1.0 / (1.0 + exp(-((pa[j]        + (double)bih[j])        + (pb[j]        + (double)bhh[j]))));
    double z = 1.0 / (1.0 + exp(-((pa[NH + j]   + (double)bih[NH + j])   + (pb[NH + j]   + (double)bhh[NH + j]))));
    double n = tanh((pa[2*NH + j] + (double)bih[2*NH + j]) + r * (pb[2*NH + j] + (double)bhh[2*NH + j]));
    h[j] = (1.0 - z) * n + z * h[j];
}

// Head partial via exact IN=2 collapse (f64): thread (s = tid&127, half = tid>>7)
// computes part[half*NH+s] = sum_{h in half*64..+64} act(c0*A0[h]+c1*A1[h]+q[h]) * v[h]
// where q[h] already contains Ab[h] + (rnn-side column dot).
template<bool TANH>
__device__ __forceinline__ void head_phase(const double* __restrict__ A0, const double* __restrict__ A1,
        const double* __restrict__ q, const float* __restrict__ vf,
        const float* __restrict__ c0, const float* __restrict__ c1,
        double* __restrict__ part, int tid)
{
    int s = tid & (NH - 1), half = tid >> 7;
    if (s >= NS) return;
    double c0s = (double)c0[s], c1s = (double)c1[s];
    const int h0 = half * 64;
    double a = 0.0;
    #pragma unroll 4
    for (int i = 0; i < 64; ++i) {
        int h = h0 + i;
        double pre = fma(c0s, A0[h], fma(c1s, A1[h], q[h]));
        double act = TANH ? tanh(pre) : fmax(pre, 0.0);
        a = fma(act, (double)vf[h], a);
    }
    part[half * NH + s] = a;
}

__global__ __launch_bounds__(NTHR) void vae_v8(
    const float* __restrict__ instance, const int* __restrict__ sol1,
    const int* __restrict__ sol2, const float* __restrict__ eps,
    const float* __restrict__ emb_i_W, const float* __restrict__ emb_i_b,
    const float* __restrict__ emb_r_W, const float* __restrict__ emb_r_b,
    const float* __restrict__ attn_W, const float* __restrict__ attn_v,
    const float* __restrict__ gru_Wih, const float* __restrict__ gru_Whh,
    const float* __restrict__ gru_bih, const float* __restrict__ gru_bhh,
    const float* __restrict__ grud_Wih, const float* __restrict__ grud_Whh,
    const float* __restrict__ grud_bih, const float* __restrict__ grud_bhh,
    const float* __restrict__ efc1_W, const float* __restrict__ efc1_b,
    const float* __restrict__ efc2_W, const float* __restrict__ efc2_b,
    const float* __restrict__ ptr_W, const float* __restrict__ ptr_v,
    const float* __restrict__ pfc1_W, const float* __restrict__ pfc1_b,
    const float* __restrict__ pfc2_W, const float* __restrict__ pfc2_b,
    float* __restrict__ out)
{
    __shared__ double s_x[360];                 // enc: [ref|ctx]; dec: [ctx|Z|ref]
    __shared__ double s_h1[NH], s_h2[NH], s_fco[NH];
    __shared__ double s_fch[256];
    __shared__ double s_pa[3 * NH], s_pb[3 * NH];
    __shared__ double s_qh[NH];                 // Ab + rnn-side q (per step, per head)
    __shared__ double d_A0a[NH], d_A1a[NH], d_Aba[NH];  // attn collapse (f64, exact algebra)
    __shared__ double d_A0p[NH], d_A1p[NH], d_Abp[NH];  // ptr collapse
    __shared__ float  s_lg[NS], s_a[NS];        // f32 logits / probs (round-5 semantics)
    __shared__ float  s_c0[NS], s_c1[NS], s_msk[NS];
    __shared__ float  t_wi0[NH], t_wi1[NH], t_bi[NH];
    __shared__ float  t_wr0[NH], t_wr1[NH], t_br[NH];
    __shared__ float  t_va[NH], t_vp[NH];
    __shared__ double s_rc[2];
    __shared__ double s_ms[2];                  // mx, se scratch (serial phases)

    const int tid = threadIdx.x;
    const int b = blockIdx.x;
    const int j = tid & (NH - 1);
    const int half = tid >> 7;

    // ---------- init ----------
    if (tid < NH) {
        t_wi0[tid] = emb_i_W[2*tid]; t_wi1[tid] = emb_i_W[2*tid+1]; t_bi[tid] = emb_i_b[tid];
        t_wr0[tid] = emb_r_W[2*tid]; t_wr1[tid] = emb_r_W[2*tid+1]; t_br[tid] = emb_r_b[tid];
        t_va[tid] = attn_v[tid]; t_vp[tid] = ptr_v[tid];
        s_h1[tid] = 0.0; s_h2[tid] = 0.0;
    }
    if (tid < NS) {
        s_c0[tid] = instance[(size_t)(b * NS + tid) * 2 + 0];
        s_c1[tid] = instance[(size_t)(b * NS + tid) * 2 + 1];
    }
    __syncthreads();
    {   // collapse tables: A0[j] = sum_k wi0[k]*W[k][j], etc. (f64 exact algebra)
        const float* Wm = (half == 0) ? attn_W : ptr_W;
        double a0 = 0.0, a1 = 0.0, ab = 0.0;
        for (int k = 0; k < NH; ++k) {
            double wv = (double)Wm[(size_t)k * NH + j];
            a0 = fma((double)t_wi0[k], wv, a0);
            a1 = fma((double)t_wi1[k], wv, a1);
            ab = fma((double)t_bi[k],  wv, ab);
        }
        if (half == 0) { d_A0a[j] = a0; d_A1a[j] = a1; d_Aba[j] = ab; }
        else           { d_A0p[j] = a0; d_A1p[j] = a1; d_Abp[j] = ab; }
    }
    if (tid < NH) {   // initial encoder ref_h
        int sp = sol1[b * NS + 0];
        s_x[tid] = (double)s_c0[sp] * (double)t_wr0[tid] + (double)s_c1[sp] * (double)t_wr1[tid] + (double)t_br[tid];
    }
    __syncthreads();

    // ---------- encoder ----------
    for (int t = 1; t < NS; ++t) {
        // GRU1 gate dots
        if (half == 0) {
            s_pa[j]        = dotw<32>(gru_Wih + (size_t)j          * NH, s_x);
            s_pa[NH + j]   = dotw<32>(gru_Wih + (size_t)(NH + j)   * NH, s_x);
            s_pa[2*NH + j] = dotw<32>(gru_Wih + (size_t)(2*NH + j) * NH, s_x);
        } else {
            s_pb[j]        = dotw<32>(gru_Whh + (size_t)j          * NH, s_h1);
            s_pb[NH + j]   = dotw<32>(gru_Whh + (size_t)(NH + j)   * NH, s_h1);
            s_pb[2*NH + j] = dotw<32>(gru_Whh + (size_t)(2*NH + j) * NH, s_h1);
        }
        __syncthreads();
        if (tid < NH) gru_combine(gru_bih, gru_bhh, s_pa, s_pb, s_h1, tid);
        __syncthreads();
        {   // q partials over k-halves (coalesced column reads)
            const float* col = attn_W + (size_t)NH * NH + j;
            double a = 0.0; const int k0 = half * 64;
            for (int k = k0; k < k0 + 64; ++k) a = fma((double)col[(size_t)k * NH], s_h1[k], a);
            s_pa[half * NH + j] = a;
        }
        __syncthreads();
        if (tid < NH) s_qh[tid] = d_Aba[tid] + (s_pa[tid] + s_pa[NH + tid]);
        __syncthreads();
        head_phase<false>(d_A0a, d_A1a, s_qh, t_va, s_c0, s_c1, s_pb, tid);
        __syncthreads();
        if (tid < NS) s_lg[tid] = (float)(s_pb[tid] + s_pb[NH + tid]);   // f32 logits
        __syncthreads();
        // ---- attention softmax, serial round-5 semantics ----
        if (tid == 0) {
            double mx = -1e308;
            for (int s = 0; s < NS; ++s) if ((double)s_lg[s] > mx) mx = (double)s_lg[s];
            s_ms[0] = mx;
        }
        __syncthreads();
        if (tid < NS) s_a[tid] = (float)exp((double)s_lg[tid] - s_ms[0]);
        __syncthreads();
        if (tid == 0) {
            double se = 0.0;
            for (int s = 0; s < NS; ++s) se += (double)s_a[s];
            s_ms[1] = se;
        }
        __syncthreads();
        if (tid < NS) s_a[tid] = (float)((double)s_a[tid] / s_ms[1]);
        __syncthreads();
        if (tid < NH) {   // context + new ref_h
            double a = 0.0;
            for (int s = 0; s < NS; ++s) {
                float ih = fmaf(s_c0[s], t_wi0[tid], fmaf(s_c1[s], t_wi1[tid], t_bi[tid]));
                a += (double)s_a[s] * (double)ih;
            }
            int sp = sol1[b * NS + t];
            s_x[NH + tid] = a;
            s_x[tid] = (double)s_c0[sp] * (double)t_wr0[tid] + (double)s_c1[sp] * (double)t_wr1[tid] + (double)t_br[tid];
        }
        __syncthreads();
        // GRUd (K=256)
        if (half == 0) {
            s_pa[j]        = dotw<64>(grud_Wih + (size_t)j          * 256, s_x);
            s_pa[NH + j]   = dotw<64>(grud_Wih + (size_t)(NH + j)   * 256, s_x);
            s_pa[2*NH + j] = dotw<64>(grud_Wih + (size_t)(2*NH + j) * 256, s_x);
        } else {
            s_pb[j]        = dotw<32>(grud_Whh + (size_t)j          * NH, s_h2);
            s_pb[NH + j]   = dotw<32>(grud_Whh + (size_t)(NH + j)   * NH, s_h2);
            s_pb[2*NH + j] = dotw<32>(grud_Whh + (size_t)(2*NH + j) * NH, s_h2);
        }
        __syncthreads();
        if (tid < NH) gru_combine(grud_bih, grud_bhh, s_pa, s_pb, s_h2, tid);
        __syncthreads();
    }

    // ---------- epilogue: mu, lv, Z ----------
    if (tid < NS) {
        int s = tid;
        double mu = dotw<32>(efc1_W + (size_t)s * NH, s_h2) + (double)efc1_b[s];
        double lv = dotw<32>(efc2_W + (size_t)s * NH, s_h2) + (double)efc2_b[s];
        double z  = mu + (double)eps[(size_t)b * NS + s] * exp(0.5 * lv);
        out[OUT_MU + b * NS + s] = (float)mu;
        out[OUT_LV + b * NS + s] = (float)lv;
        out[OUT_Z  + b * NS + s] = (float)z;
        s_x[NH + s] = z;   // decoder Z slot [128..227]
    }
    if (tid < NS) s_msk[tid] = 1.f;
    if (tid < NH) s_h1[tid] = 0.0;
    __syncthreads();
    if (tid == 0) {
        int s0 = sol2[b * NS + 0];
        s_msk[s0] = 0.f;
        s_rc[0] = (double)s_c0[s0];
        s_rc[1] = (double)s_c1[s0];
        out[OUT_TI + b * NS + 0] = (float)s0;
    }
    __syncthreads();

    // ---------- decoder ----------
    for (int t = 1; t < NS; ++t) {
        if (tid < NH)
            s_x[228 + tid] = s_rc[0] * (double)t_wr0[tid] + s_rc[1] * (double)t_wr1[tid] + (double)t_br[tid];
        __syncthreads();
        // GRU1 on ref (K=128)
        if (half == 0) {
            s_pa[j]        = dotw<32>(gru_Wih + (size_t)j          * NH, s_x + 228);
            s_pa[NH + j]   = dotw<32>(gru_Wih + (size_t)(NH + j)   * NH, s_x + 228);
            s_pa[2*NH + j] = dotw<32>(gru_Wih + (size_t)(2*NH + j) * NH, s_x + 228);
        } else {
            s_pb[j]        = dotw<32>(gru_Whh + (size_t)j          * NH, s_h1);
            s_pb[NH + j]   = dotw<32>(gru_Whh + (size_t)(NH + j)   * NH, s_h1);
            s_pb[2*NH + j] = dotw<32>(gru_Whh + (size_t)(2*NH + j) * NH, s_h1);
        }
        __syncthreads();
        if (tid < NH) gru_combine(gru_bih, gru_bhh, s_pa, s_pb, s_h1, tid);
        __syncthreads();
        {   // q partials (attn)
            const float* col = attn_W + (size_t)NH * NH + j;
            double a = 0.0; const int k0 = half * 64;
            for (int k = k0; k < k0 + 64; ++k) a = fma((double)col[(size_t)k * NH], s_h1[k], a);
            s_pa[half * NH + j] = a;
        }
        __syncthreads();
        if (tid < NH) s_qh[tid] = d_Aba[tid] + (s_pa[tid] + s_pa[NH + tid]);
        __syncthreads();
        head_phase<false>(d_A0a, d_A1a, s_qh, t_va, s_c0, s_c1, s_pb, tid);
        __syncthreads();
        if (tid < NS) s_lg[tid] = (float)(s_pb[tid] + s_pb[NH + tid]);
        __syncthreads();
        if (tid == 0) {
            double mx = -1e308;
            for (int s = 0; s < NS; ++s) if ((double)s_lg[s] > mx) mx = (double)s_lg[s];
            s_ms[0] = mx;
        }
        __syncthreads();
        if (tid < NS) s_a[tid] = (float)exp((double)s_lg[tid] - s_ms[0]);
        __syncthreads();
        if (tid == 0) {
            double se = 0.0;
            for (int s = 0; s < NS; ++s) se += (double)s_a[s];
            s_ms[1] = se;
        }
        __syncthreads();
        if (tid < NS) s_a[tid] = (float)((double)s_a[tid] / s_ms[1]);
        __syncthreads();
        if (tid < NH) {   // context -> s_x[0..127]
            double a = 0.0;
            for (int s = 0; s < NS; ++s) {
                float ih = fmaf(s_c0[s], t_wi0[tid], fmaf(s_c1[s], t_wi1[tid], t_bi[tid]));
                a += (double)s_a[s] * (double)ih;
            }
            s_x[tid] = a;
        }
        __syncthreads();
        {   // pfc1: 256 rows, K=356 over [ctx|Z|ref]
            double a = dotw<89>(pfc1_W + (size_t)tid * 356, s_x);
            s_fch[tid] = a + (double)pfc1_b[tid];
        }
        __syncthreads();
        {   // pfc2 partials: K=256 split in halves
            double a = dotw<32>(pfc2_W + (size_t)j * 256 + half * 128, s_fch + half * 128);
            s_pa[half * NH + j] = a;
        }
        __syncthreads();
        if (tid < NH) s_fco[tid] = (s_pa[tid] + s_pa[NH + tid]) + (double)pfc2_b[tid];
        __syncthreads();
        {   // q2 partials (ptr)
            const float* col = ptr_W + (size_t)NH * NH + j;
            double a = 0.0; const int k0 = half * 64;
            for (int k = k0; k < k0 + 64; ++k) a = fma((double)col[(size_t)k * NH], s_fco[k], a);
            s_pa[half * NH + j] = a;
        }
        __syncthreads();
        if (tid < NH) s_qh[tid] = d_Abp[tid] + (s_pa[tid] + s_pa[NH + tid]);
        __syncthreads();
        head_phase<true>(d_A0p, d_A1p, s_qh, t_vp, s_c0, s_c1, s_pb, tid);
        __syncthreads();
        if (tid < NS) s_lg[tid] = (float)(s_pb[tid] + s_pb[NH + tid]);
        __syncthreads();
        // ---- masked softmax / argmax / logp, serial round-5 semantics ----
        if (tid == 0) {
            double mx = -1e308;
            for (int s = 0; s < NS; ++s) {
                double v = (s_msk[s] > 0.f) ? (double)s_lg[s] : -1e308;
                if (v > mx) mx = v;
            }
            s_ms[0] = mx;
        }
        __syncthreads();
        if (tid < NS)
            s_a[tid] = (s_msk[tid] > 0.f) ? (float)exp((double)s_lg[tid] - s_ms[0]) : 0.f;
        __syncthreads();
        if (tid == 0) {
            int pt = sol2[b * NS + t];
            double se = 0.0;
            for (int s = 0; s < NS; ++s) se += (double)s_a[s];
            double bp = -1.0; int bidx = 0;
            for (int s = 0; s < NS; ++s) {
                double p = (double)s_a[s] / se;
                if (p > bp) { bp = p; bidx = s; }
            }
            double logp = log(((double)s_a[pt]) / se);
            out[OUT_TI + b * NS + t]             = (float)bidx;
            out[OUT_LP + b * (NS - 1) + (t - 1)] = (float)logp;
            s_msk[pt] = 0.f;
            s_rc[0] = (double)s_c0[pt];
            s_rc[1] = (double)s_c1[pt];
        }
        __syncthreads();
    }
}

extern "C" void kernel_launch(void* const* d_in, const int* in_sizes, int n_in,
                              void* d_out, int out_size, void* d_ws, size_t ws_size,
                              hipStream_t stream)
{
    (void)in_sizes; (void)n_in; (void)out_size; (void)d_ws; (void)ws_size;
    vae_v8<<<NB, NTHR, 0, stream>>>(
        (const float*)d_in[0], (const int*)d_in[1], (const int*)d_in[2], (const float*)d_in[3],
        (const float*)d_in[4], (const float*)d_in[5], (const float*)d_in[6], (const float*)d_in[7],
        (const float*)d_in[8], (const float*)d_in[9], (const float*)d_in[10], (const float*)d_in[11],
        (const float*)d_in[12], (const float*)d_in[13], (const float*)d_in[14], (const float*)d_in[15],
        (const float*)d_in[16], (const float*)d_in[17], (const float*)d_in[18], (const float*)d_in[19],
        (const float*)d_in[20], (const float*)d_in[21], (const float*)d_in[22], (const float*)d_in[23],
        (const float*)d_in[24], (const float*)d_in[25], (const float*)d_in[26], (const float*)d_in[27],
        (float*)d_out);
}

// Round 9
// 14267.699 us; speedup vs baseline: 9.6944x; 3.1830x over previous
//
#include <hip/hip_runtime.h>
#include <math.h>

static constexpr int NB  = 1024;
static constexpr int NS  = 100;
static constexpr int NH  = 128;
static constexpr int GPB = 2;      // batches per block (weight-row reuse)
static constexpr int NTHR = 256;
static constexpr int NBLK = NB / GPB;   // 512 blocks -> 2 blocks/CU

static constexpr int OUT_MU = 0;
static constexpr int OUT_LV = NB * NS;
static constexpr int OUT_Z  = 2 * NB * NS;
static constexpr int OUT_TI = 3 * NB * NS;
static constexpr int OUT_LP = 4 * NB * NS;

// f32 dot of one f32 weight row (C4 float4 chunks) against TWO f32 LDS vectors
// (row loaded once -> both batches).
template<int C4>
__device__ __forceinline__ void dot2f(const float* __restrict__ w,
                                      const float* __restrict__ x0, const float* __restrict__ x1,
                                      float& r0, float& r1)
{
    const float4* W = reinterpret_cast<const float4*>(w);
    float a0 = 0.f, a1 = 0.f;
    #pragma unroll 8
    for (int c = 0; c < C4; ++c) {
        float4 u = W[c];
        const float* p0 = x0 + 4 * c;
        const float* p1 = x1 + 4 * c;
        a0 = fmaf(u.x, p0[0], a0); a0 = fmaf(u.y, p0[1], a0);
        a0 = fmaf(u.z, p0[2], a0); a0 = fmaf(u.w, p0[3], a0);
        a1 = fmaf(u.x, p1[0], a1); a1 = fmaf(u.y, p1[1], a1);
        a1 = fmaf(u.z, p1[2], a1); a1 = fmaf(u.w, p1[3], a1);
    }
    r0 = a0; r1 = a1;
}

// f64-accum dot of an f32 row vs f32 LDS vector (for mu/lv epilogue).
template<int C4>
__device__ __forceinline__ double dotwd(const float* __restrict__ w, const float* __restrict__ x)
{
    const float4* W = reinterpret_cast<const float4*>(w);
    double a = 0.0;
    #pragma unroll 8
    for (int c = 0; c < C4; ++c) {
        float4 u = W[c];
        const float* p = x + 4 * c;
        a = fma((double)u.x, (double)p[0], a);
        a = fma((double)u.y, (double)p[1], a);
        a = fma((double)u.z, (double)p[2], a);
        a = fma((double)u.w, (double)p[3], a);
    }
    return a;
}

// f32 dot (single vector), f32 accum — pfc2.
template<int C4>
__device__ __forceinline__ float dot1f(const float* __restrict__ w, const float* __restrict__ x)
{
    const float4* W = reinterpret_cast<const float4*>(w);
    float a = 0.f;
    #pragma unroll 8
    for (int c = 0; c < C4; ++c) {
        float4 u = W[c];
        const float* p = x + 4 * c;
        a = fmaf(u.x, p[0], a); a = fmaf(u.y, p[1], a);
        a = fmaf(u.z, p[2], a); a = fmaf(u.w, p[3], a);
    }
    return a;
}

// GRU nonlinearity (f64 internals, f32 storage): pa = x-side dots, pb = h-side.
__device__ __forceinline__ void gru_combine(const float* __restrict__ bih, const float* __restrict__ bhh,
        const float* __restrict__ pa, const float* __restrict__ pb, float* __restrict__ h, int j)
{
    double r = 1.0 / (1.0 + exp(-(((double)pa[j]        + (double)bih[j])        + ((double)pb[j]        + (double)bhh[j]))));
    double z = 1.0 / (1.0 + exp(-(((double)pa[NH + j]   + (double)bih[NH + j])   + ((double)pb[NH + j]   + (double)bhh[NH + j]))));
    double n = tanh(((double)pa[2*NH + j] + (double)bih[2*NH + j]) + r * ((double)pb[2*NH + j] + (double)bhh[2*NH + j]));
    h[j] = (float)((1.0 - z) * n + z * (double)h[j]);
}

__global__ __launch_bounds__(NTHR) void vae_v9(
    const float* __restrict__ instance, const int* __restrict__ sol1,
    const int* __restrict__ sol2, const float* __restrict__ eps,
    const float* __restrict__ emb_i_W, const float* __restrict__ emb_i_b,
    const float* __restrict__ emb_r_W, const float* __restrict__ emb_r_b,
    const float* __restrict__ attn_W, const float* __restrict__ attn_v,
    const float* __restrict__ gru_Wih, const float* __restrict__ gru_Whh,
    const float* __restrict__ gru_bih, const float* __restrict__ gru_bhh,
    const float* __restrict__ grud_Wih, const float* __restrict__ grud_Whh,
    const float* __restrict__ grud_bih, const float* __restrict__ grud_bhh,
    const float* __restrict__ efc1_W, const float* __restrict__ efc1_b,
    const float* __restrict__ efc2_W, const float* __restrict__ efc2_b,
    const float* __restrict__ ptr_W, const float* __restrict__ ptr_v,
    const float* __restrict__ pfc1_W, const float* __restrict__ pfc1_b,
    const float* __restrict__ pfc2_W, const float* __restrict__ pfc2_b,
    float* __restrict__ out)
{
    __shared__ float  s_x[GPB][360];            // enc: [ref|ctx]; dec: [ctx|Z|ref]
    __shared__ float  s_h1[GPB][NH], s_h2[GPB][NH], s_fco[GPB][NH];
    __shared__ float  s_fch[GPB][256];
    __shared__ float  s_pa[GPB][3 * NH], s_pb[GPB][3 * NH];
    __shared__ double s_qh[GPB][NH];            // Ab + rnn-side q (f64, per step)
    __shared__ double dA0a[NH], dA1a[NH], dAba[NH];   // attn collapse (f64 exact)
    __shared__ double dA0p[NH], dA1p[NH], dAbp[NH];   // ptr collapse
    __shared__ float  s_lg[GPB][NS], s_a[GPB][NS];
    __shared__ float  s_c0[GPB][NS], s_c1[GPB][NS], s_msk[GPB][NS];
    __shared__ float  t_wi0[NH], t_wi1[NH], t_bi[NH];
    __shared__ float  t_wr0[NH], t_wr1[NH], t_br[NH];
    __shared__ float  t_va[NH], t_vp[NH];
    __shared__ float  s_rc0[GPB], s_rc1[GPB];
    __shared__ double s_mx[GPB], s_se[GPB];

    const int tid = threadIdx.x;
    const int bbase = blockIdx.x * GPB;
    const int j = tid & (NH - 1);
    const int half = tid >> 7;                  // doubles as batch index g in (g,j) phases

    // ---------- init ----------
    if (tid < NH) {
        t_wi0[tid] = emb_i_W[2*tid]; t_wi1[tid] = emb_i_W[2*tid+1]; t_bi[tid] = emb_i_b[tid];
        t_wr0[tid] = emb_r_W[2*tid]; t_wr1[tid] = emb_r_W[2*tid+1]; t_br[tid] = emb_r_b[tid];
        t_va[tid] = attn_v[tid]; t_vp[tid] = ptr_v[tid];
    }
    for (int i = tid; i < GPB * NS; i += NTHR) {
        int g = i / NS, s = i - g * NS;
        s_c0[g][s] = instance[(size_t)((bbase + g) * NS + s) * 2 + 0];
        s_c1[g][s] = instance[(size_t)((bbase + g) * NS + s) * 2 + 1];
    }
    s_h1[half][j] = 0.f;
    s_h2[half][j] = 0.f;
    __syncthreads();
    {   // collapse tables (f64 exact algebra, same as R8)
        const float* Wm = (half == 0) ? attn_W : ptr_W;
        double a0 = 0.0, a1 = 0.0, ab = 0.0;
        for (int k = 0; k < NH; ++k) {
            double wv = (double)Wm[(size_t)k * NH + j];
            a0 = fma((double)t_wi0[k], wv, a0);
            a1 = fma((double)t_wi1[k], wv, a1);
            ab = fma((double)t_bi[k],  wv, ab);
        }
        if (half == 0) { dA0a[j] = a0; dA1a[j] = a1; dAba[j] = ab; }
        else           { dA0p[j] = a0; dA1p[j] = a1; dAbp[j] = ab; }
    }
    {   // initial encoder ref_h per batch
        int sp = sol1[(bbase + half) * NS + 0];
        s_x[half][j] = fmaf(s_c0[half][sp], t_wr0[j], fmaf(s_c1[half][sp], t_wr1[j], t_br[j]));
    }
    __syncthreads();

    // ---------- encoder ----------
    for (int t = 1; t < NS; ++t) {
        // GRU1 gate dots: half0 = x-side (both batches), half1 = h-side (both batches)
        if (half == 0) {
            float r0, r1;
            dot2f<32>(gru_Wih + (size_t)j          * NH, s_x[0], s_x[1], r0, r1); s_pa[0][j] = r0;        s_pa[1][j] = r1;
            dot2f<32>(gru_Wih + (size_t)(NH + j)   * NH, s_x[0], s_x[1], r0, r1); s_pa[0][NH + j] = r0;   s_pa[1][NH + j] = r1;
            dot2f<32>(gru_Wih + (size_t)(2*NH + j) * NH, s_x[0], s_x[1], r0, r1); s_pa[0][2*NH + j] = r0; s_pa[1][2*NH + j] = r1;
        } else {
            float r0, r1;
            dot2f<32>(gru_Whh + (size_t)j          * NH, s_h1[0], s_h1[1], r0, r1); s_pb[0][j] = r0;        s_pb[1][j] = r1;
            dot2f<32>(gru_Whh + (size_t)(NH + j)   * NH, s_h1[0], s_h1[1], r0, r1); s_pb[0][NH + j] = r0;   s_pb[1][NH + j] = r1;
            dot2f<32>(gru_Whh + (size_t)(2*NH + j) * NH, s_h1[0], s_h1[1], r0, r1); s_pb[0][2*NH + j] = r0; s_pb[1][2*NH + j] = r1;
        }
        __syncthreads();
        gru_combine(gru_bih, gru_bhh, s_pa[half], s_pb[half], s_h1[half], j);
        __syncthreads();
        {   // q[g][j] = Aba[j] + h1[g] . attn_W[128:256][:,j]  (f64 accum)
            const float* col = attn_W + (size_t)NH * NH + j;
            double a = 0.0;
            for (int k = 0; k < NH; ++k) a = fma((double)col[(size_t)k * NH], (double)s_h1[half][k], a);
            s_qh[half][j] = dAba[j] + a;
        }
        __syncthreads();
        if (j < NS) {   // relu head logits (g = half, s = j); R8 math
            double c0s = (double)s_c0[half][j], c1s = (double)s_c1[half][j];
            double acc = 0.0;
            for (int h = 0; h < NH; ++h) {
                double pre = fma(c0s, dA0a[h], fma(c1s, dA1a[h], s_qh[half][h]));
                acc = fma(fmax(pre, 0.0), (double)t_va[h], acc);
            }
            s_lg[half][j] = (float)acc;
        }
        __syncthreads();
        // ---- attention softmax, serial semantics (verbatim R8, per batch) ----
        if (tid < GPB) {
            double mx = -1e308;
            for (int s = 0; s < NS; ++s) if ((double)s_lg[tid][s] > mx) mx = (double)s_lg[tid][s];
            s_mx[tid] = mx;
        }
        __syncthreads();
        if (j < NS) s_a[half][j] = (float)exp((double)s_lg[half][j] - s_mx[half]);
        __syncthreads();
        if (tid < GPB) {
            double se = 0.0;
            for (int s = 0; s < NS; ++s) se += (double)s_a[tid][s];
            s_se[tid] = se;
        }
        __syncthreads();
        if (j < NS) s_a[half][j] = (float)((double)s_a[half][j] / s_se[half]);
        __syncthreads();
        {   // context + new ref_h (g = half, j)
            double a = 0.0;
            for (int s = 0; s < NS; ++s) {
                float ih = fmaf(s_c0[half][s], t_wi0[j], fmaf(s_c1[half][s], t_wi1[j], t_bi[j]));
                a += (double)s_a[half][s] * (double)ih;
            }
            int sp = sol1[(bbase + half) * NS + t];
            s_x[half][NH + j] = (float)a;
            s_x[half][j] = fmaf(s_c0[half][sp], t_wr0[j], fmaf(s_c1[half][sp], t_wr1[j], t_br[j]));
        }
        __syncthreads();
        // GRUd (K=256 x-side)
        if (half == 0) {
            float r0, r1;
            dot2f<64>(grud_Wih + (size_t)j          * 256, s_x[0], s_x[1], r0, r1); s_pa[0][j] = r0;        s_pa[1][j] = r1;
            dot2f<64>(grud_Wih + (size_t)(NH + j)   * 256, s_x[0], s_x[1], r0, r1); s_pa[0][NH + j] = r0;   s_pa[1][NH + j] = r1;
            dot2f<64>(grud_Wih + (size_t)(2*NH + j) * 256, s_x[0], s_x[1], r0, r1); s_pa[0][2*NH + j] = r0; s_pa[1][2*NH + j] = r1;
        } else {
            float r0, r1;
            dot2f<32>(grud_Whh + (size_t)j          * NH, s_h2[0], s_h2[1], r0, r1); s_pb[0][j] = r0;        s_pb[1][j] = r1;
            dot2f<32>(grud_Whh + (size_t)(NH + j)   * NH, s_h2[0], s_h2[1], r0, r1); s_pb[0][NH + j] = r0;   s_pb[1][NH + j] = r1;
            dot2f<32>(grud_Whh + (size_t)(2*NH + j) * NH, s_h2[0], s_h2[1], r0, r1); s_pb[0][2*NH + j] = r0; s_pb[1][2*NH + j] = r1;
        }
        __syncthreads();
        gru_combine(grud_bih, grud_bhh, s_pa[half], s_pb[half], s_h2[half], j);
        __syncthreads();
    }

    // ---------- epilogue: mu, lv, Z ----------
    if (j < NS) {
        int s = j, b = bbase + half;
        double mu = dotwd<32>(efc1_W + (size_t)s * NH, s_h2[half]) + (double)efc1_b[s];
        double lv = dotwd<32>(efc2_W + (size_t)s * NH, s_h2[half]) + (double)efc2_b[s];
        double z  = mu + (double)eps[(size_t)b * NS + s] * exp(0.5 * lv);
        out[OUT_MU + b * NS + s] = (float)mu;
        out[OUT_LV + b * NS + s] = (float)lv;
        out[OUT_Z  + b * NS + s] = (float)z;
        s_x[half][NH + s] = (float)z;   // decoder Z slot [128..227]
    }
    for (int i = tid; i < GPB * NS; i += NTHR) {
        int g = i / NS, s = i - g * NS;
        s_msk[g][s] = 1.f;
    }
    s_h1[half][j] = 0.f;
    __syncthreads();
    if (tid < GPB) {
        int b = bbase + tid;
        int s0 = sol2[b * NS + 0];
        s_msk[tid][s0] = 0.f;
        s_rc0[tid] = s_c0[tid][s0];
        s_rc1[tid] = s_c1[tid][s0];
        out[OUT_TI + b * NS + 0] = (float)s0;
    }
    __syncthreads();

    // ---------- decoder ----------
    for (int t = 1; t < NS; ++t) {
        s_x[half][228 + j] = fmaf(s_rc0[half], t_wr0[j], fmaf(s_rc1[half], t_wr1[j], t_br[j]));
        __syncthreads();
        // GRU1 on ref (K=128)
        if (half == 0) {
            float r0, r1;
            dot2f<32>(gru_Wih + (size_t)j          * NH, s_x[0] + 228, s_x[1] + 228, r0, r1); s_pa[0][j] = r0;        s_pa[1][j] = r1;
            dot2f<32>(gru_Wih + (size_t)(NH + j)   * NH, s_x[0] + 228, s_x[1] + 228, r0, r1); s_pa[0][NH + j] = r0;   s_pa[1][NH + j] = r1;
            dot2f<32>(gru_Wih + (size_t)(2*NH + j) * NH, s_x[0] + 228, s_x[1] + 228, r0, r1); s_pa[0][2*NH + j] = r0; s_pa[1][2*NH + j] = r1;
        } else {
            float r0, r1;
            dot2f<32>(gru_Whh + (size_t)j          * NH, s_h1[0], s_h1[1], r0, r1); s_pb[0][j] = r0;        s_pb[1][j] = r1;
            dot2f<32>(gru_Whh + (size_t)(NH + j)   * NH, s_h1[0], s_h1[1], r0, r1); s_pb[0][NH + j] = r0;   s_pb[1][NH + j] = r1;
            dot2f<32>(gru_Whh + (size_t)(2*NH + j) * NH, s_h1[0], s_h1[1], r0, r1); s_pb[0][2*NH + j] = r0; s_pb[1][2*NH + j] = r1;
        }
        __syncthreads();
        gru_combine(gru_bih, gru_bhh, s_pa[half], s_pb[half], s_h1[half], j);
        __syncthreads();
        {   // q (attn)
            const float* col = attn_W + (size_t)NH * NH + j;
            double a = 0.0;
            for (int k = 0; k < NH; ++k) a = fma((double)col[(size_t)k * NH], (double)s_h1[half][k], a);
            s_qh[half][j] = dAba[j] + a;
        }
        __syncthreads();
        if (j < NS) {   // relu head
            double c0s = (double)s_c0[half][j], c1s = (double)s_c1[half][j];
            double acc = 0.0;
            for (int h = 0; h < NH; ++h) {
                double pre = fma(c0s, dA0a[h], fma(c1s, dA1a[h], s_qh[half][h]));
                acc = fma(fmax(pre, 0.0), (double)t_va[h], acc);
            }
            s_lg[half][j] = (float)acc;
        }
        __syncthreads();
        if (tid < GPB) {
            double mx = -1e308;
            for (int s = 0; s < NS; ++s) if ((double)s_lg[tid][s] > mx) mx = (double)s_lg[tid][s];
            s_mx[tid] = mx;
        }
        __syncthreads();
        if (j < NS) s_a[half][j] = (float)exp((double)s_lg[half][j] - s_mx[half]);
        __syncthreads();
        if (tid < GPB) {
            double se = 0.0;
            for (int s = 0; s < NS; ++s) se += (double)s_a[tid][s];
            s_se[tid] = se;
        }
        __syncthreads();
        if (j < NS) s_a[half][j] = (float)((double)s_a[half][j] / s_se[half]);
        __syncthreads();
        {   // context -> s_x[g][0..127]
            double a = 0.0;
            for (int s = 0; s < NS; ++s) {
                float ih = fmaf(s_c0[half][s], t_wi0[j], fmaf(s_c1[half][s], t_wi1[j], t_bi[j]));
                a += (double)s_a[half][s] * (double)ih;
            }
            s_x[half][j] = (float)a;
        }
        __syncthreads();
        {   // pfc1: row i = tid, both batches (row read once)
            float r0, r1;
            dot2f<89>(pfc1_W + (size_t)tid * 356, s_x[0], s_x[1], r0, r1);
            float bb = pfc1_b[tid];
            s_fch[0][tid] = r0 + bb;
            s_fch[1][tid] = r1 + bb;
        }
        __syncthreads();
        // pfc2: (g = half, j)
        s_fco[half][j] = dot1f<64>(pfc2_W + (size_t)j * 256, s_fch[half]) + pfc2_b[j];
        __syncthreads();
        {   // q2 (ptr)
            const float* col = ptr_W + (size_t)NH * NH + j;
            double a = 0.0;
            for (int k = 0; k < NH; ++k) a = fma((double)col[(size_t)k * NH], (double)s_fco[half][k], a);
            s_qh[half][j] = dAbp[j] + a;
        }
        __syncthreads();
        if (j < NS) {   // tanh pointer head (tanhf on f64 pre)
            double c0s = (double)s_c0[half][j], c1s = (double)s_c1[half][j];
            double acc = 0.0;
            for (int h = 0; h < NH; ++h) {
                double pre = fma(c0s, dA0p[h], fma(c1s, dA1p[h], s_qh[half][h]));
                acc = fma((double)tanhf((float)pre), (double)t_vp[h], acc);
            }
            s_lg[half][j] = (float)acc;
        }
        __syncthreads();
        // ---- masked softmax / argmax / logp, serial semantics (verbatim R8, per batch) ----
        if (tid < GPB) {
            double mx = -1e308;
            for (int s = 0; s < NS; ++s) {
                double v = (s_msk[tid][s] > 0.f) ? (double)s_lg[tid][s] : -1e308;
                if (v > mx) mx = v;
            }
            s_mx[tid] = mx;
        }
        __syncthreads();
        if (j < NS)
            s_a[half][j] = (s_msk[half][j] > 0.f) ? (float)exp((double)s_lg[half][j] - s_mx[half]) : 0.f;
        __syncthreads();
        if (tid < GPB) {
            int b = bbase + tid;
            int pt = sol2[b * NS + t];
            double se = 0.0;
            for (int s = 0; s < NS; ++s) se += (double)s_a[tid][s];
            double bp = -1.0; int bidx = 0;
            for (int s = 0; s < NS; ++s) {
                double p = (double)s_a[tid][s] / se;
                if (p > bp) { bp = p; bidx = s; }
            }
            double logp = log(((double)s_a[tid][pt]) / se);
            out[OUT_TI + b * NS + t]             = (float)bidx;
            out[OUT_LP + b * (NS - 1) + (t - 1)] = (float)logp;
            s_msk[tid][pt] = 0.f;
            s_rc0[tid] = s_c0[tid][pt];
            s_rc1[tid] = s_c1[tid][pt];
        }
        __syncthreads();
    }
}

extern "C" void kernel_launch(void* const* d_in, const int* in_sizes, int n_in,
                              void* d_out, int out_size, void* d_ws, size_t ws_size,
                              hipStream_t stream)
{
    (void)in_sizes; (void)n_in; (void)out_size; (void)d_ws; (void)ws_size;
    vae_v9<<<NBLK, NTHR, 0, stream>>>(
        (const float*)d_in[0], (const int*)d_in[1], (const int*)d_in[2], (const float*)d_in[3],
        (const float*)d_in[4], (const float*)d_in[5], (const float*)d_in[6], (const float*)d_in[7],
        (const float*)d_in[8], (const float*)d_in[9], (const float*)d_in[10], (const float*)d_in[11],
        (const float*)d_in[12], (const float*)d_in[13], (const float*)d_in[14], (const float*)d_in[15],
        (const float*)d_in[16], (const float*)d_in[17], (const float*)d_in[18], (const float*)d_in[19],
        (const float*)d_in[20], (const float*)d_in[21], (const float*)d_in[22], (const float*)d_in[23],
        (const float*)d_in[24], (const float*)d_in[25], (const float*)d_in[26], (const float*)d_in[27],
        (float*)d_out);
}

// Round 11
// 14169.006 us; speedup vs baseline: 9.7619x; 1.0070x over previous
//
#include <hip/hip_runtime.h>
#include <math.h>

static constexpr int NB  = 1024;
static constexpr int NS  = 100;
static constexpr int NH  = 128;
static constexpr int GPB = 4;           // batches per block (1 weight read -> 4 batches)
static constexpr int NTHR = 256;
static constexpr int NBLK = NB / GPB;   // 256 blocks = 1 per CU

static constexpr int OUT_MU = 0;
static constexpr int OUT_LV = NB * NS;
static constexpr int OUT_Z  = 2 * NB * NS;
static constexpr int OUT_TI = 3 * NB * NS;
static constexpr int OUT_LP = 4 * NB * NS;

#define NEGF (-3.4e38f)

// f32 dot of one f32 weight row against FOUR f32 LDS vectors (row loaded once).
// Per-accumulator fmaf chain identical to R9's dot2f (k ascending).
template<int C4>
__device__ __forceinline__ void dot4f(const float* __restrict__ w,
        const float* __restrict__ x0, const float* __restrict__ x1,
        const float* __restrict__ x2, const float* __restrict__ x3,
        float& r0, float& r1, float& r2, float& r3)
{
    const float4* W = reinterpret_cast<const float4*>(w);
    float a0 = 0.f, a1 = 0.f, a2 = 0.f, a3 = 0.f;
    #pragma unroll 4
    for (int c = 0; c < C4; ++c) {
        float4 u = W[c];
        int k = 4 * c;
        a0 = fmaf(u.x, x0[k], a0); a0 = fmaf(u.y, x0[k+1], a0); a0 = fmaf(u.z, x0[k+2], a0); a0 = fmaf(u.w, x0[k+3], a0);
        a1 = fmaf(u.x, x1[k], a1); a1 = fmaf(u.y, x1[k+1], a1); a1 = fmaf(u.z, x1[k+2], a1); a1 = fmaf(u.w, x1[k+3], a1);
        a2 = fmaf(u.x, x2[k], a2); a2 = fmaf(u.y, x2[k+1], a2); a2 = fmaf(u.z, x2[k+2], a2); a2 = fmaf(u.w, x2[k+3], a2);
        a3 = fmaf(u.x, x3[k], a3); a3 = fmaf(u.y, x3[k+1], a3); a3 = fmaf(u.z, x3[k+2], a3); a3 = fmaf(u.w, x3[k+3], a3);
    }
    r0 = a0; r1 = a1; r2 = a2; r3 = a3;
}

template<int C4>
__device__ __forceinline__ void dot2f(const float* __restrict__ w,
        const float* __restrict__ x0, const float* __restrict__ x1, float& r0, float& r1)
{
    const float4* W = reinterpret_cast<const float4*>(w);
    float a0 = 0.f, a1 = 0.f;
    #pragma unroll 8
    for (int c = 0; c < C4; ++c) {
        float4 u = W[c];
        int k = 4 * c;
        a0 = fmaf(u.x, x0[k], a0); a0 = fmaf(u.y, x0[k+1], a0); a0 = fmaf(u.z, x0[k+2], a0); a0 = fmaf(u.w, x0[k+3], a0);
        a1 = fmaf(u.x, x1[k], a1); a1 = fmaf(u.y, x1[k+1], a1); a1 = fmaf(u.z, x1[k+2], a1); a1 = fmaf(u.w, x1[k+3], a1);
    }
    r0 = a0; r1 = a1;
}

// f64-accum dot of an f32 row vs f32 LDS vector (mu/lv epilogue) — R9 verbatim.
template<int C4>
__device__ __forceinline__ double dotwd(const float* __restrict__ w, const float* __restrict__ x)
{
    const float4* W = reinterpret_cast<const float4*>(w);
    double a = 0.0;
    #pragma unroll 8
    for (int c = 0; c < C4; ++c) {
        float4 u = W[c];
        const float* p = x + 4 * c;
        a = fma((double)u.x, (double)p[0], a);
        a = fma((double)u.y, (double)p[1], a);
        a = fma((double)u.z, (double)p[2], a);
        a = fma((double)u.w, (double)p[3], a);
    }
    return a;
}

// GRU nonlinearity (f64 internals, f32 storage) — R9 verbatim.
__device__ __forceinline__ void gruc(const float* __restrict__ bih, const float* __restrict__ bhh,
        const float* __restrict__ pa, const float* __restrict__ pb, float* __restrict__ h, int j)
{
    double r = 1.0 / (1.0 + exp(-(((double)pa[j]        + (double)bih[j])        + ((double)pb[j]        + (double)bhh[j]))));
    double z = 1.0 / (1.0 + exp(-(((double)pa[NH + j]   + (double)bih[NH + j])   + ((double)pb[NH + j]   + (double)bhh[NH + j]))));
    double n = tanh(((double)pa[2*NH + j] + (double)bih[2*NH + j]) + r * ((double)pb[2*NH + j] + (double)bhh[2*NH + j]));
    h[j] = (float)((1.0 - z) * n + z * (double)h[j]);
}

__global__ __launch_bounds__(NTHR) void vae_v11(
    const float* __restrict__ instance, const int* __restrict__ sol1,
    const int* __restrict__ sol2, const float* __restrict__ eps,
    const float* __restrict__ emb_i_W, const float* __restrict__ emb_i_b,
    const float* __restrict__ emb_r_W, const float* __restrict__ emb_r_b,
    const float* __restrict__ attn_W, const float* __restrict__ attn_v,
    const float* __restrict__ gru_Wih, const float* __restrict__ gru_Whh,
    const float* __restrict__ gru_bih, const float* __restrict__ gru_bhh,
    const float* __restrict__ grud_Wih, const float* __restrict__ grud_Whh,
    const float* __restrict__ grud_bih, const float* __restrict__ grud_bhh,
    const float* __restrict__ efc1_W, const float* __restrict__ efc1_b,
    const float* __restrict__ efc2_W, const float* __restrict__ efc2_b,
    const float* __restrict__ ptr_W, const float* __restrict__ ptr_v,
    const float* __restrict__ pfc1_W, const float* __restrict__ pfc1_b,
    const float* __restrict__ pfc2_W, const float* __restrict__ pfc2_b,
    float* __restrict__ out)
{
    __shared__ float  s_x[GPB][360];            // enc: [ref|ctx]; dec: [ctx|Z|ref]
    __shared__ float  s_h1[GPB][NH], s_h2[GPB][NH], s_fco[GPB][NH];
    __shared__ float  s_fch[GPB][256];
    __shared__ float  s_pa[GPB][3 * NH], s_pb[GPB][3 * NH];
    __shared__ double s_qh[GPB][NH];            // Ab + rnn-side q (f64, R9 semantics)
    __shared__ double dA0a[NH], dA1a[NH], dAba[NH];   // attn collapse (f64)
    __shared__ double dA0p[NH], dA1p[NH], dAbp[NH];   // ptr collapse (f64)
    __shared__ float  s_lg[GPB][NS], s_a[GPB][NS];
    __shared__ float  s_c0[GPB][NS], s_c1[GPB][NS], s_msk[GPB][NS];
    __shared__ float  t_wi0[NH], t_wi1[NH], t_bi[NH];
    __shared__ float  t_wr0[NH], t_wr1[NH], t_br[NH];
    __shared__ float  t_va[NH], t_vp[NH];
    __shared__ float  s_red[GPB][16];           // f32 max partials
    __shared__ double s_redd[GPB][16];          // f64 sum partials
    __shared__ int    s_ri[GPB][16];
    __shared__ float  s_mx[GPB];
    __shared__ double s_se[GPB];
    __shared__ int    s_aid[GPB];
    __shared__ float  s_rc0[GPB], s_rc1[GPB];

    const int tid = threadIdx.x;
    const int bbase = blockIdx.x * GPB;
    const int j = tid & (NH - 1);
    const int half = tid >> 7;
    const int g0 = half, g1 = half + 2;

    // ---------- init ----------
    if (tid < NH) {
        t_wi0[tid] = emb_i_W[2*tid]; t_wi1[tid] = emb_i_W[2*tid+1]; t_bi[tid] = emb_i_b[tid];
        t_wr0[tid] = emb_r_W[2*tid]; t_wr1[tid] = emb_r_W[2*tid+1]; t_br[tid] = emb_r_b[tid];
        t_va[tid] = attn_v[tid]; t_vp[tid] = ptr_v[tid];
    }
    for (int i = tid; i < GPB * NS; i += NTHR) {
        int g = i / NS, s = i - g * NS;
        s_c0[g][s] = instance[(size_t)((bbase + g) * NS + s) * 2 + 0];
        s_c1[g][s] = instance[(size_t)((bbase + g) * NS + s) * 2 + 1];
    }
    s_h1[g0][j] = 0.f; s_h1[g1][j] = 0.f;
    s_h2[g0][j] = 0.f; s_h2[g1][j] = 0.f;
    __syncthreads();
    {   // collapse tables: f64 exact algebra (R9 verbatim)
        const float* Wm = (half == 0) ? attn_W : ptr_W;
        double a0 = 0.0, a1 = 0.0, ab = 0.0;
        for (int k = 0; k < NH; ++k) {
            double wv = (double)Wm[(size_t)k * NH + j];
            a0 = fma((double)t_wi0[k], wv, a0);
            a1 = fma((double)t_wi1[k], wv, a1);
            ab = fma((double)t_bi[k],  wv, ab);
        }
        if (half == 0) { dA0a[j] = a0; dA1a[j] = a1; dAba[j] = ab; }
        else           { dA0p[j] = a0; dA1p[j] = a1; dAbp[j] = ab; }
    }
    {   // initial encoder ref_h
        int sp0 = sol1[(bbase + g0) * NS + 0];
        int sp1 = sol1[(bbase + g1) * NS + 0];
        s_x[g0][j] = fmaf(s_c0[g0][sp0], t_wr0[j], fmaf(s_c1[g0][sp0], t_wr1[j], t_br[j]));
        s_x[g1][j] = fmaf(s_c0[g1][sp1], t_wr0[j], fmaf(s_c1[g1][sp1], t_wr1[j], t_br[j]));
    }
    __syncthreads();

    // ---------- encoder ----------
    for (int t = 1; t < NS; ++t) {
        if (half == 0) {    // GRU1 x-side: one row read -> 4 batches
            float r0, r1, r2, r3;
            dot4f<32>(gru_Wih + (size_t)j          * NH, s_x[0], s_x[1], s_x[2], s_x[3], r0, r1, r2, r3);
            s_pa[0][j] = r0; s_pa[1][j] = r1; s_pa[2][j] = r2; s_pa[3][j] = r3;
            dot4f<32>(gru_Wih + (size_t)(NH + j)   * NH, s_x[0], s_x[1], s_x[2], s_x[3], r0, r1, r2, r3);
            s_pa[0][NH + j] = r0; s_pa[1][NH + j] = r1; s_pa[2][NH + j] = r2; s_pa[3][NH + j] = r3;
            dot4f<32>(gru_Wih + (size_t)(2*NH + j) * NH, s_x[0], s_x[1], s_x[2], s_x[3], r0, r1, r2, r3);
            s_pa[0][2*NH + j] = r0; s_pa[1][2*NH + j] = r1; s_pa[2][2*NH + j] = r2; s_pa[3][2*NH + j] = r3;
        } else {            // GRU1 h-side
            float r0, r1, r2, r3;
            dot4f<32>(gru_Whh + (size_t)j          * NH, s_h1[0], s_h1[1], s_h1[2], s_h1[3], r0, r1, r2, r3);
            s_pb[0][j] = r0; s_pb[1][j] = r1; s_pb[2][j] = r2; s_pb[3][j] = r3;
            dot4f<32>(gru_Whh + (size_t)(NH + j)   * NH, s_h1[0], s_h1[1], s_h1[2], s_h1[3], r0, r1, r2, r3);
            s_pb[0][NH + j] = r0; s_pb[1][NH + j] = r1; s_pb[2][NH + j] = r2; s_pb[3][NH + j] = r3;
            dot4f<32>(gru_Whh + (size_t)(2*NH + j) * NH, s_h1[0], s_h1[1], s_h1[2], s_h1[3], r0, r1, r2, r3);
            s_pb[0][2*NH + j] = r0; s_pb[1][2*NH + j] = r1; s_pb[2][2*NH + j] = r2; s_pb[3][2*NH + j] = r3;
        }
        __syncthreads();
        gruc(gru_bih, gru_bhh, s_pa[g0], s_pb[g0], s_h1[g0], j);
        gruc(gru_bih, gru_bhh, s_pa[g1], s_pb[g1], s_h1[g1], j);
        __syncthreads();
        {   // q = Ab + h1 . attn_W[128:256] columns (f64 accum, R9 verbatim)
            const float* col = attn_W + (size_t)NH * NH + j;
            double a0 = 0.0, a1 = 0.0;
            for (int k = 0; k < NH; ++k) {
                double wv = (double)col[(size_t)k * NH];
                a0 = fma(wv, (double)s_h1[g0][k], a0);
                a1 = fma(wv, (double)s_h1[g1][k], a1);
            }
            s_qh[g0][j] = dAba[j] + a0;
            s_qh[g1][j] = dAba[j] + a1;
        }
        __syncthreads();
        if (j < NS) {   // relu head logits (f64 pre/accum, R9 verbatim)
            double c00 = (double)s_c0[g0][j], c10 = (double)s_c1[g0][j];
            double c01 = (double)s_c0[g1][j], c11 = (double)s_c1[g1][j];
            double acc0 = 0.0, acc1 = 0.0;
            for (int h = 0; h < NH; ++h) {
                double A0 = dA0a[h], A1 = dA1a[h], v = (double)t_va[h];
                double p0 = fma(c00, A0, fma(c10, A1, s_qh[g0][h]));
                double p1 = fma(c01, A0, fma(c11, A1, s_qh[g1][h]));
                acc0 = fma(fmax(p0, 0.0), v, acc0);
                acc1 = fma(fmax(p1, 0.0), v, acc1);
            }
            s_lg[g0][j] = (float)acc0;
            s_lg[g1][j] = (float)acc1;
        }
        __syncthreads();
        if (j < 16) {   // segmented max (exact, order-free)
            float m0 = NEGF, m1 = NEGF;
            for (int s = j; s < NS; s += 16) { m0 = fmaxf(m0, s_lg[g0][s]); m1 = fmaxf(m1, s_lg[g1][s]); }
            s_red[g0][j] = m0; s_red[g1][j] = m1;
        }
        __syncthreads();
        if (tid < GPB) {
            float m = NEGF;
            for (int i = 0; i < 16; ++i) m = fmaxf(m, s_red[tid][i]);
            s_mx[tid] = m;
        }
        __syncthreads();
        if (j < NS) {   // exps: f64 exp narrowed to f32 (R9 semantics)
            s_a[g0][j] = (float)exp((double)s_lg[g0][j] - (double)s_mx[g0]);
            s_a[g1][j] = (float)exp((double)s_lg[g1][j] - (double)s_mx[g1]);
        }
        __syncthreads();
        if (j < 16) {   // segmented f64 sum
            double t0 = 0.0, t1 = 0.0;
            for (int s = j; s < NS; s += 16) { t0 += (double)s_a[g0][s]; t1 += (double)s_a[g1][s]; }
            s_redd[g0][j] = t0; s_redd[g1][j] = t1;
        }
        __syncthreads();
        if (tid < GPB) {
            double se = 0.0;
            for (int i = 0; i < 16; ++i) se += s_redd[tid][i];
            s_se[tid] = se;
        }
        __syncthreads();
        if (j < NS) {   // normalize first (R9 semantics)
            s_a[g0][j] = (float)((double)s_a[g0][j] / s_se[g0]);
            s_a[g1][j] = (float)((double)s_a[g1][j] / s_se[g1]);
        }
        __syncthreads();
        {   // context (f64 accum of f32 probs x f32 ih, R9 verbatim) + new ref_h
            float w0 = t_wi0[j], w1 = t_wi1[j], bb = t_bi[j];
            double a0 = 0.0, a1 = 0.0;
            for (int s = 0; s < NS; ++s) {
                float ih0 = fmaf(s_c0[g0][s], w0, fmaf(s_c1[g0][s], w1, bb));
                float ih1 = fmaf(s_c0[g1][s], w0, fmaf(s_c1[g1][s], w1, bb));
                a0 += (double)s_a[g0][s] * (double)ih0;
                a1 += (double)s_a[g1][s] * (double)ih1;
            }
            s_x[g0][NH + j] = (float)a0;
            s_x[g1][NH + j] = (float)a1;
            int sp0 = sol1[(bbase + g0) * NS + t];
            int sp1 = sol1[(bbase + g1) * NS + t];
            s_x[g0][j] = fmaf(s_c0[g0][sp0], t_wr0[j], fmaf(s_c1[g0][sp0], t_wr1[j], t_br[j]));
            s_x[g1][j] = fmaf(s_c0[g1][sp1], t_wr0[j], fmaf(s_c1[g1][sp1], t_wr1[j], t_br[j]));
        }
        __syncthreads();
        if (half == 0) {    // GRUd x-side (K=256)
            float r0, r1, r2, r3;
            dot4f<64>(grud_Wih + (size_t)j          * 256, s_x[0], s_x[1], s_x[2], s_x[3], r0, r1, r2, r3);
            s_pa[0][j] = r0; s_pa[1][j] = r1; s_pa[2][j] = r2; s_pa[3][j] = r3;
            dot4f<64>(grud_Wih + (size_t)(NH + j)   * 256, s_x[0], s_x[1], s_x[2], s_x[3], r0, r1, r2, r3);
            s_pa[0][NH + j] = r0; s_pa[1][NH + j] = r1; s_pa[2][NH + j] = r2; s_pa[3][NH + j] = r3;
            dot4f<64>(grud_Wih + (size_t)(2*NH + j) * 256, s_x[0], s_x[1], s_x[2], s_x[3], r0, r1, r2, r3);
            s_pa[0][2*NH + j] = r0; s_pa[1][2*NH + j] = r1; s_pa[2][2*NH + j] = r2; s_pa[3][2*NH + j] = r3;
        } else {            // GRUd h-side
            float r0, r1, r2, r3;
            dot4f<32>(grud_Whh + (size_t)j          * NH, s_h2[0], s_h2[1], s_h2[2], s_h2[3], r0, r1, r2, r3);
            s_pb[0][j] = r0; s_pb[1][j] = r1; s_pb[2][j] = r2; s_pb[3][j] = r3;
            dot4f<32>(grud_Whh + (size_t)(NH + j)   * NH, s_h2[0], s_h2[1], s_h2[2], s_h2[3], r0, r1, r2, r3);
            s_pb[0][NH + j] = r0; s_pb[1][NH + j] = r1; s_pb[2][NH + j] = r2; s_pb[3][NH + j] = r3;
            dot4f<32>(grud_Whh + (size_t)(2*NH + j) * NH, s_h2[0], s_h2[1], s_h2[2], s_h2[3], r0, r1, r2, r3);
            s_pb[0][2*NH + j] = r0; s_pb[1][2*NH + j] = r1; s_pb[2][2*NH + j] = r2; s_pb[3][2*NH + j] = r3;
        }
        __syncthreads();
        gruc(grud_bih, grud_bhh, s_pa[g0], s_pb[g0], s_h2[g0], j);
        gruc(grud_bih, grud_bhh, s_pa[g1], s_pb[g1], s_h2[g1], j);
        __syncthreads();
    }

    // ---------- epilogue: mu, lv, Z (f64, R9 verbatim) ----------
    for (int idx = tid; idx < GPB * NS; idx += NTHR) {
        int g = idx / NS, s = idx - g * NS, b = bbase + g;
        double mu = dotwd<32>(efc1_W + (size_t)s * NH, s_h2[g]) + (double)efc1_b[s];
        double lv = dotwd<32>(efc2_W + (size_t)s * NH, s_h2[g]) + (double)efc2_b[s];
        double z  = mu + (double)eps[(size_t)b * NS + s] * exp(0.5 * lv);
        out[OUT_MU + b * NS + s] = (float)mu;
        out[OUT_LV + b * NS + s] = (float)lv;
        out[OUT_Z  + b * NS + s] = (float)z;
        s_x[g][NH + s] = (float)z;   // decoder Z slot [128..227]
    }
    for (int i = tid; i < GPB * NS; i += NTHR) {
        int g = i / NS, s = i - g * NS;
        s_msk[g][s] = 1.f;
    }
    s_h1[g0][j] = 0.f; s_h1[g1][j] = 0.f;
    __syncthreads();
    if (tid < GPB) {
        int b = bbase + tid;
        int s0 = sol2[b * NS + 0];
        s_msk[tid][s0] = 0.f;
        s_rc0[tid] = s_c0[tid][s0];
        s_rc1[tid] = s_c1[tid][s0];
        out[OUT_TI + b * NS + 0] = (float)s0;
    }
    __syncthreads();

    // ---------- decoder ----------
    for (int t = 1; t < NS; ++t) {
        s_x[g0][228 + j] = fmaf(s_rc0[g0], t_wr0[j], fmaf(s_rc1[g0], t_wr1[j], t_br[j]));
        s_x[g1][228 + j] = fmaf(s_rc0[g1], t_wr0[j], fmaf(s_rc1[g1], t_wr1[j], t_br[j]));
        __syncthreads();
        if (half == 0) {    // GRU1 x-side on ref
            float r0, r1, r2, r3;
            dot4f<32>(gru_Wih + (size_t)j          * NH, s_x[0]+228, s_x[1]+228, s_x[2]+228, s_x[3]+228, r0, r1, r2, r3);
            s_pa[0][j] = r0; s_pa[1][j] = r1; s_pa[2][j] = r2; s_pa[3][j] = r3;
            dot4f<32>(gru_Wih + (size_t)(NH + j)   * NH, s_x[0]+228, s_x[1]+228, s_x[2]+228, s_x[3]+228, r0, r1, r2, r3);
            s_pa[0][NH + j] = r0; s_pa[1][NH + j] = r1; s_pa[2][NH + j] = r2; s_pa[3][NH + j] = r3;
            dot4f<32>(gru_Wih + (size_t)(2*NH + j) * NH, s_x[0]+228, s_x[1]+228, s_x[2]+228, s_x[3]+228, r0, r1, r2, r3);
            s_pa[0][2*NH + j] = r0; s_pa[1][2*NH + j] = r1; s_pa[2][2*NH + j] = r2; s_pa[3][2*NH + j] = r3;
        } else {
            float r0, r1, r2, r3;
            dot4f<32>(gru_Whh + (size_t)j          * NH, s_h1[0], s_h1[1], s_h1[2], s_h1[3], r0, r1, r2, r3);
            s_pb[0][j] = r0; s_pb[1][j] = r1; s_pb[2][j] = r2; s_pb[3][j] = r3;
            dot4f<32>(gru_Whh + (size_t)(NH + j)   * NH, s_h1[0], s_h1[1], s_h1[2], s_h1[3], r0, r1, r2, r3);
            s_pb[0][NH + j] = r0; s_pb[1][NH + j] = r1; s_pb[2][NH + j] = r2; s_pb[3][NH + j] = r3;
            dot4f<32>(gru_Whh + (size_t)(2*NH + j) * NH, s_h1[0], s_h1[1], s_h1[2], s_h1[3], r0, r1, r2, r3);
            s_pb[0][2*NH + j] = r0; s_pb[1][2*NH + j] = r1; s_pb[2][2*NH + j] = r2; s_pb[3][2*NH + j] = r3;
        }
        __syncthreads();
        gruc(gru_bih, gru_bhh, s_pa[g0], s_pb[g0], s_h1[g0], j);
        gruc(gru_bih, gru_bhh, s_pa[g1], s_pb[g1], s_h1[g1], j);
        __syncthreads();
        {   // q (attn, f64)
            const float* col = attn_W + (size_t)NH * NH + j;
            double a0 = 0.0, a1 = 0.0;
            for (int k = 0; k < NH; ++k) {
                double wv = (double)col[(size_t)k * NH];
                a0 = fma(wv, (double)s_h1[g0][k], a0);
                a1 = fma(wv, (double)s_h1[g1][k], a1);
            }
            s_qh[g0][j] = dAba[j] + a0;
            s_qh[g1][j] = dAba[j] + a1;
        }
        __syncthreads();
        if (j < NS) {   // relu head (f64)
            double c00 = (double)s_c0[g0][j], c10 = (double)s_c1[g0][j];
            double c01 = (double)s_c0[g1][j], c11 = (double)s_c1[g1][j];
            double acc0 = 0.0, acc1 = 0.0;
            for (int h = 0; h < NH; ++h) {
                double A0 = dA0a[h], A1 = dA1a[h], v = (double)t_va[h];
                double p0 = fma(c00, A0, fma(c10, A1, s_qh[g0][h]));
                double p1 = fma(c01, A0, fma(c11, A1, s_qh[g1][h]));
                acc0 = fma(fmax(p0, 0.0), v, acc0);
                acc1 = fma(fmax(p1, 0.0), v, acc1);
            }
            s_lg[g0][j] = (float)acc0;
            s_lg[g1][j] = (float)acc1;
        }
        __syncthreads();
        if (j < 16) {
            float m0 = NEGF, m1 = NEGF;
            for (int s = j; s < NS; s += 16) { m0 = fmaxf(m0, s_lg[g0][s]); m1 = fmaxf(m1, s_lg[g1][s]); }
            s_red[g0][j] = m0; s_red[g1][j] = m1;
        }
        __syncthreads();
        if (tid < GPB) {
            float m = NEGF;
            for (int i = 0; i < 16; ++i) m = fmaxf(m, s_red[tid][i]);
            s_mx[tid] = m;
        }
        __syncthreads();
        if (j < NS) {
            s_a[g0][j] = (float)exp((double)s_lg[g0][j] - (double)s_mx[g0]);
            s_a[g1][j] = (float)exp((double)s_lg[g1][j] - (double)s_mx[g1]);
        }
        __syncthreads();
        if (j < 16) {
            double t0 = 0.0, t1 = 0.0;
            for (int s = j; s < NS; s += 16) { t0 += (double)s_a[g0][s]; t1 += (double)s_a[g1][s]; }
            s_redd[g0][j] = t0; s_redd[g1][j] = t1;
        }
        __syncthreads();
        if (tid < GPB) {
            double se = 0.0;
            for (int i = 0; i < 16; ++i) se += s_redd[tid][i];
            s_se[tid] = se;
        }
        __syncthreads();
        if (j < NS) {
            s_a[g0][j] = (float)((double)s_a[g0][j] / s_se[g0]);
            s_a[g1][j] = (float)((double)s_a[g1][j] / s_se[g1]);
        }
        __syncthreads();
        {   // context -> s_x[g][0..127]
            float w0 = t_wi0[j], w1 = t_wi1[j], bb = t_bi[j];
            double a0 = 0.0, a1 = 0.0;
            for (int s = 0; s < NS; ++s) {
                float ih0 = fmaf(s_c0[g0][s], w0, fmaf(s_c1[g0][s], w1, bb));
                float ih1 = fmaf(s_c0[g1][s], w0, fmaf(s_c1[g1][s], w1, bb));
                a0 += (double)s_a[g0][s] * (double)ih0;
                a1 += (double)s_a[g1][s] * (double)ih1;
            }
            s_x[g0][j] = (float)a0;
            s_x[g1][j] = (float)a1;
        }
        __syncthreads();
        {   // pfc1: row i = tid, one read -> 4 batches (f32, R9 chain)
            float r0, r1, r2, r3;
            dot4f<89>(pfc1_W + (size_t)tid * 356, s_x[0], s_x[1], s_x[2], s_x[3], r0, r1, r2, r3);
            float bb = pfc1_b[tid];
            s_fch[0][tid] = r0 + bb; s_fch[1][tid] = r1 + bb;
            s_fch[2][tid] = r2 + bb; s_fch[3][tid] = r3 + bb;
        }
        __syncthreads();
        {   // pfc2 (f32)
            float r0, r1;
            dot2f<64>(pfc2_W + (size_t)j * 256, s_fch[g0], s_fch[g1], r0, r1);
            s_fco[g0][j] = r0 + pfc2_b[j];
            s_fco[g1][j] = r1 + pfc2_b[j];
        }
        __syncthreads();
        {   // q2 (ptr, f64)
            const float* col = ptr_W + (size_t)NH * NH + j;
            double a0 = 0.0, a1 = 0.0;
            for (int k = 0; k < NH; ++k) {
                double wv = (double)col[(size_t)k * NH];
                a0 = fma(wv, (double)s_fco[g0][k], a0);
                a1 = fma(wv, (double)s_fco[g1][k], a1);
            }
            s_qh[g0][j] = dAbp[j] + a0;
            s_qh[g1][j] = dAbp[j] + a1;
        }
        __syncthreads();
        if (j < NS) {   // tanh pointer head (f64 pre, tanhf, R9 verbatim)
            double c00 = (double)s_c0[g0][j], c10 = (double)s_c1[g0][j];
            double c01 = (double)s_c0[g1][j], c11 = (double)s_c1[g1][j];
            double acc0 = 0.0, acc1 = 0.0;
            for (int h = 0; h < NH; ++h) {
                double A0 = dA0p[h], A1 = dA1p[h], v = (double)t_vp[h];
                double p0 = fma(c00, A0, fma(c10, A1, s_qh[g0][h]));
                double p1 = fma(c01, A0, fma(c11, A1, s_qh[g1][h]));
                acc0 = fma((double)tanhf((float)p0), v, acc0);
                acc1 = fma((double)tanhf((float)p1), v, acc1);
            }
            s_lg[g0][j] = (float)acc0;
            s_lg[g1][j] = (float)acc1;
        }
        __syncthreads();
        if (j < 16) {   // masked segmented max of logits (for exp stability only)
            float m0 = NEGF, m1 = NEGF;
            for (int s = j; s < NS; s += 16) {
                float v0 = (s_msk[g0][s] > 0.f) ? s_lg[g0][s] : NEGF;
                float v1 = (s_msk[g1][s] > 0.f) ? s_lg[g1][s] : NEGF;
                m0 = fmaxf(m0, v0);
                m1 = fmaxf(m1, v1);
            }
            s_red[g0][j] = m0; s_red[g1][j] = m1;
        }
        __syncthreads();
        if (tid < GPB) {
            float m = NEGF;
            for (int i = 0; i < 16; ++i) m = fmaxf(m, s_red[tid][i]);
            s_mx[tid] = m;
        }
        __syncthreads();
        if (j < NS) {   // masked exps, f64 exp narrowed to f32 (R9 semantics)
            s_a[g0][j] = (s_msk[g0][j] > 0.f) ? (float)exp((double)s_lg[g0][j] - (double)s_mx[g0]) : 0.f;
            s_a[g1][j] = (s_msk[g1][j] > 0.f) ? (float)exp((double)s_lg[g1][j] - (double)s_mx[g1]) : 0.f;
        }
        __syncthreads();
        if (j < 16) {   // KEY FIX: argmax over f32 EXPS (prob-equivalent), first-occurrence ties
            float m0 = -1.f, m1 = -1.f; int i0 = 0, i1 = 0;
            double t0 = 0.0, t1 = 0.0;
            for (int s = j; s < NS; s += 16) {
                float a0v = s_a[g0][s], a1v = s_a[g1][s];
                t0 += (double)a0v; t1 += (double)a1v;
                if (a0v > m0) { m0 = a0v; i0 = s; }
                if (a1v > m1) { m1 = a1v; i1 = s; }
            }
            s_red[g0][j] = m0; s_ri[g0][j] = i0; s_redd[g0][j] = t0;
            s_red[g1][j] = m1; s_ri[g1][j] = i1; s_redd[g1][j] = t1;
        }
        __syncthreads();
        if (tid < GPB) {   // fold: first-occurrence argmax + se; outputs + carry
            int g = tid, b = bbase + g;
            float m = -1.f; int mi = NS; double se = 0.0;
            for (int i = 0; i < 16; ++i) {
                se += s_redd[g][i];
                float v = s_red[g][i]; int vi = s_ri[g][i];
                if (v > m || (v == m && vi < mi)) { m = v; mi = vi; }
            }
            int pt = sol2[b * NS + t];
            double logp = log((double)s_a[g][pt] / se);
            out[OUT_TI + b * NS + t]             = (float)mi;
            out[OUT_LP + b * (NS - 1) + (t - 1)] = (float)logp;
            s_msk[g][pt] = 0.f;
            s_rc0[g] = s_c0[g][pt];
            s_rc1[g] = s_c1[g][pt];
        }
        __syncthreads();
    }
}

extern "C" void kernel_launch(void* const* d_in, const int* in_sizes, int n_in,
                              void* d_out, int out_size, void* d_ws, size_t ws_size,
                              hipStream_t stream)
{
    (void)in_sizes; (void)n_in; (void)out_size; (void)d_ws; (void)ws_size;
    vae_v11<<<NBLK, NTHR, 0, stream>>>(
        (const float*)d_in[0], (const int*)d_in[1], (const int*)d_in[2], (const float*)d_in[3],
        (const float*)d_in[4], (const float*)d_in[5], (const float*)d_in[6], (const float*)d_in[7],
        (const float*)d_in[8], (const float*)d_in[9], (const float*)d_in[10], (const float*)d_in[11],
        (const float*)d_in[12], (const float*)d_in[13], (const float*)d_in[14], (const float*)d_in[15],
        (const float*)d_in[16], (const float*)d_in[17], (const float*)d_in[18], (const float*)d_in[19],
        (const float*)d_in[20], (const float*)d_in[21], (const float*)d_in[22], (const float*)d_in[23],
        (const float*)d_in[24], (const float*)d_in[25], (const float*)d_in[26], (const float*)d_in[27],
        (float*)d_out);
}